// Round 9
// baseline (1050.452 us; speedup 1.0000x reference)
//
#include <hip/hip_runtime.h>

#define NN 100000
#define NE 1600000
#define BSH 9
#define NBUK 196          // ceil(NN / 512)
#define TBATCH 4          // nodes per ticket grab

typedef __attribute__((ext_vector_type(8))) short bf16x8;
typedef __attribute__((ext_vector_type(4))) float f32x4;

__device__ __forceinline__ float grp_sum16(float v){
  #pragma unroll
  for (int o = 8; o; o >>= 1) v += __shfl_xor(v, o, 16);
  return v;
}
__device__ __forceinline__ float grp_sum32(float v){
  #pragma unroll
  for (int o = 16; o; o >>= 1) v += __shfl_xor(v, o, 32);
  return v;
}
__device__ __forceinline__ float bf2f(unsigned short x){
  return __uint_as_float(((unsigned)x) << 16);
}
__device__ __forceinline__ unsigned short f2bf(float f){
  unsigned u = __float_as_uint(f);
  return (unsigned short)((u + 0x7FFFu + ((u >> 16) & 1u)) >> 16);
}

// ---- weight prep: transpose + bf16. Wmlt interleaved: col 2c=Wmu[:,c], 2c+1=Wls[:,c] ----
__global__ void prep_w_kernel(const float* __restrict__ W1, const float* __restrict__ W2,
                              const float* __restrict__ Wr, const float* __restrict__ Wmu,
                              const float* __restrict__ Wls,
                              unsigned short* __restrict__ W1t, unsigned short* __restrict__ W2t,
                              unsigned short* __restrict__ Wrt, unsigned short* __restrict__ Wmlt){
  int b = blockIdx.x, t = threadIdx.x;
  for (int it = 0; it < 64; it++){
    int idx = it*256 + t;          // 16384 entries
    int k = idx >> 7, c = idx & 127;
    float v; unsigned short* dst;
    if (b == 0){ v = W1[k*128+c]; dst = W1t; }
    else if (b == 1){ v = W2[k*128+c]; dst = W2t; }
    else if (b == 2){ v = Wr[k*128+c]; dst = Wrt; }
    else { v = (c & 1) ? Wls[k*64 + (c>>1)] : Wmu[k*64 + (c>>1)]; dst = Wmlt; }
    dst[c*128 + k] = f2bf(v);      // [col][k]
  }
}

__global__ void wvec_kernel(const float* __restrict__ We2, const float* __restrict__ ae2,
                            const float* __restrict__ Wemu, const float* __restrict__ aemu,
                            const float* __restrict__ Wels, const float* __restrict__ aels,
                            float* __restrict__ wv){
  int t = threadIdx.x;
  if (t < 16){
    float s = 0.f; for (int c = 0; c < 128; c++) s += We2[t*128+c]*ae2[c];
    wv[t] = s;
  } else if (t < 32){
    int k = t-16; float s = 0.f; for (int c = 0; c < 64; c++) s += Wemu[k*64+c]*aemu[c];
    wv[16+k] = s;
  } else if (t < 48){
    int k = t-32; float s = 0.f; for (int c = 0; c < 64; c++) s += Wels[k*64+c]*aels[c];
    wv[32+k] = s;
  }
}

__global__ void cast_x_kernel(const float* __restrict__ x, unsigned short* __restrict__ Xb){
  int i = blockIdx.x*256 + threadIdx.x;   // 8 elems each
  if (i >= NN*128/8) return;
  const float4* src = (const float4*)x + (size_t)i*2;
  float4 v0 = src[0], v1 = src[1];
  ushort4 o0 = make_ushort4(f2bf(v0.x), f2bf(v0.y), f2bf(v0.z), f2bf(v0.w));
  ushort4 o1 = make_ushort4(f2bf(v1.x), f2bf(v1.y), f2bf(v1.z), f2bf(v1.w));
  *(ushort4*)(Xb + (size_t)i*8)     = o0;
  *(ushort4*)(Xb + (size_t)i*8 + 4) = o1;
}

__global__ void zero_kernel(int* __restrict__ p, int n){
  int i = blockIdx.x*256 + threadIdx.x;
  if (i < n) p[i] = 0;
}

// ---- coarse 256-bucket histogram of dst>>9 (LDS aggregated) ----
__global__ __launch_bounds__(1024) void ehist_kernel(const int* __restrict__ ei,
                                                     unsigned* __restrict__ gbcnt){
  __shared__ unsigned h[256];
  int t = threadIdx.x;
  if (t < 256) h[t] = 0;
  __syncthreads();
  int e0 = blockIdx.x*4096 + t;
  #pragma unroll
  for (int k = 0; k < 4; k++){
    int e = e0 + k*1024;
    if (e < NE) atomicAdd(&h[ei[NE+e] >> BSH], 1);
  }
  __syncthreads();
  if (t < 256 && h[t]) atomicAdd(&gbcnt[t], h[t]);
}

__global__ void bscan_kernel(const unsigned* __restrict__ gbcnt,
                             unsigned* __restrict__ gbbase, int* __restrict__ rowptr){
  __shared__ unsigned sh[256];
  int t = threadIdx.x;   // 256
  unsigned v = gbcnt[t];
  sh[t] = v; __syncthreads();
  for (int o = 1; o < 256; o <<= 1){
    unsigned add = (t >= o) ? sh[t-o] : 0;
    __syncthreads();
    sh[t] += add;
    __syncthreads();
  }
  gbbase[t+1] = sh[t];
  if (t == 0){ gbbase[0] = 0; rowptr[NN] = NE; }
}

// ---- bin (+fused edge-scalar dots): append {dst,u} + {s2,smu,sls} per bucket ----
__global__ __launch_bounds__(1024) void bin_kernel(const int* __restrict__ ei,
                                                   const float* __restrict__ ea,
                                                   const float* __restrict__ wv,
                                                   const unsigned* __restrict__ gbbase,
                                                   unsigned* __restrict__ gbfill,
                                                   uint2* __restrict__ bdu,
                                                   float4* __restrict__ bw){
  __shared__ unsigned hcnt[256], hbase[256], hcur[256];
  __shared__ float wvs[48];
  int t = threadIdx.x;
  if (t < 256){ hcnt[t] = 0; hcur[t] = 0; }
  else if (t >= 256 && t < 304) wvs[t-256] = wv[t-256];
  __syncthreads();
  int d[4], u[4], b[4]; float4 w[4]; bool val[4];
  int e0 = blockIdx.x*4096 + t;
  #pragma unroll
  for (int k = 0; k < 4; k++){
    int e = e0 + k*1024;
    val[k] = e < NE;
    if (val[k]){
      d[k] = ei[NE+e]; u[k] = ei[e];
      b[k] = d[k] >> BSH;
      atomicAdd(&hcnt[b[k]], 1);
      const float4* p = (const float4*)(ea + (size_t)e*16);
      float a[16]; float4 vv;
      vv = p[0]; a[0]=vv.x; a[1]=vv.y; a[2]=vv.z; a[3]=vv.w;
      vv = p[1]; a[4]=vv.x; a[5]=vv.y; a[6]=vv.z; a[7]=vv.w;
      vv = p[2]; a[8]=vv.x; a[9]=vv.y; a[10]=vv.z; a[11]=vv.w;
      vv = p[3]; a[12]=vv.x; a[13]=vv.y; a[14]=vv.z; a[15]=vv.w;
      float s2 = 0.f, smu = 0.f, sls = 0.f;
      #pragma unroll
      for (int q = 0; q < 16; q++){
        s2  = fmaf(a[q], wvs[q],    s2);
        smu = fmaf(a[q], wvs[16+q], smu);
        sls = fmaf(a[q], wvs[32+q], sls);
      }
      w[k] = make_float4(s2, smu, sls, 0.f);
    }
  }
  __syncthreads();
  if (t < 256){
    unsigned c = hcnt[t];
    hbase[t] = c ? atomicAdd(&gbfill[t], c) : 0u;
  }
  __syncthreads();
  #pragma unroll
  for (int k = 0; k < 4; k++){
    if (val[k]){
      unsigned pos = atomicAdd(&hcur[b[k]], 1);
      unsigned slot = gbbase[b[k]] + hbase[b[k]] + pos;
      bdu[slot] = make_uint2((unsigned)d[k], (unsigned)u[k]);
      bw[slot]  = w[k];
    }
  }
}

// ---- place: per-bucket sub-rowptr in LDS + scatter into L2-resident CSR region ----
__global__ __launch_bounds__(1024) void place_kernel(const uint2* __restrict__ bdu,
                                                     const float4* __restrict__ bw,
                                                     const unsigned* __restrict__ gbbase,
                                                     int* __restrict__ rowptr,
                                                     unsigned* __restrict__ csr_u,
                                                     float* __restrict__ ewp2,
                                                     float2* __restrict__ ewpmuls){
  __shared__ unsigned h[512], incl[512], cur[512];
  int b = blockIdx.x, t = threadIdx.x;
  unsigned cbase = gbbase[b];
  unsigned cnt = gbbase[b+1] - cbase;
  if (t < 512) h[t] = 0;
  __syncthreads();
  for (unsigned i = t; i < cnt; i += 1024)
    atomicAdd(&h[bdu[cbase+i].x & 511], 1);
  __syncthreads();
  if (t < 512) incl[t] = h[t];
  __syncthreads();
  for (int o = 1; o < 512; o <<= 1){
    unsigned add = (t >= o && t < 512) ? incl[t-o] : 0;
    __syncthreads();
    if (t < 512) incl[t] += add;
    __syncthreads();
  }
  if (t < 512){
    cur[t] = 0;
    int node = (b << BSH) + t;
    if (node < NN) rowptr[node] = (int)(cbase + incl[t] - h[t]);
  }
  __syncthreads();
  for (unsigned i = t; i < cnt; i += 1024){
    uint2 du = bdu[cbase+i];
    unsigned ld = du.x & 511;
    unsigned pos = atomicAdd(&cur[ld], 1);
    unsigned slot = cbase + (incl[ld] - h[ld]) + pos;
    float4 w = bw[cbase+i];
    csr_u[slot] = du.y;
    ewp2[slot] = w.x;
    ewpmuls[slot] = make_float2(w.y, w.z);
  }
}

// ---- MFMA GEMM: Y[nrows x 128] = Xb @ Wt^T, bf16 in, fp32 acc.
//      OUT: 0=bf16, 1=f32+bias, 2=bf16+bias. DOTS: 0 none, 1 conv s/d, 2 mu/ls. ----
template<int OUT, int DOTS>
__global__ __launch_bounds__(256) void gemm_bf16(const unsigned short* __restrict__ Xb,
                                                 const unsigned short* __restrict__ Wt,
                                                 void* __restrict__ Y,
                                                 const float* __restrict__ bias, int nrows,
                                                 const float* __restrict__ va,
                                                 const float* __restrict__ vb,
                                                 const float* __restrict__ vc,
                                                 const float* __restrict__ vd,
                                                 float* __restrict__ sOut,
                                                 float* __restrict__ dOut){
  __shared__ uint4 As[128*16];   // 32 KB, XOR-swizzled chunks
  __shared__ uint4 Bs[128*16];   // 32 KB
  int t = threadIdx.x;
  int row0 = blockIdx.x * 128;
  #pragma unroll
  for (int p = 0; p < 8; p++){
    int idx = p*256 + t;
    int r = idx >> 4, cir = idx & 15;
    uint4 v = make_uint4(0,0,0,0);
    if (row0 + r < nrows) v = *(const uint4*)(Xb + ((size_t)(row0+r))*128 + cir*8);
    As[r*16 + (cir ^ (r & 7))] = v;
  }
  #pragma unroll
  for (int p = 0; p < 8; p++){
    int idx = p*256 + t;
    int r = idx >> 4, cir = idx & 15;
    Bs[r*16 + (cir ^ (r & 7))] = *(const uint4*)(Wt + (size_t)r*128 + cir*8);
  }
  __syncthreads();
  int w = t >> 6, l = t & 63;
  int lr = l & 15;
  int lk = l >> 4;
  const bf16x8* As8 = (const bf16x8*)As;
  const bf16x8* Bs8 = (const bf16x8*)Bs;
  f32x4 acc[2][8];
  f32x4 zero = {0.f, 0.f, 0.f, 0.f};
  #pragma unroll
  for (int m = 0; m < 2; m++)
    #pragma unroll
    for (int n = 0; n < 8; n++) acc[m][n] = zero;
  #pragma unroll
  for (int ks = 0; ks < 4; ks++){
    bf16x8 a0, a1, bf[8];
    { int r = w*32 + lr;      a0 = As8[r*16 + ((ks*4+lk) ^ (r&7))]; }
    { int r = w*32 + 16 + lr; a1 = As8[r*16 + ((ks*4+lk) ^ (r&7))]; }
    #pragma unroll
    for (int nt = 0; nt < 8; nt++){
      int r = nt*16 + lr;
      bf[nt] = Bs8[r*16 + ((ks*4+lk) ^ (r&7))];
    }
    #pragma unroll
    for (int nt = 0; nt < 8; nt++){
      acc[0][nt] = __builtin_amdgcn_mfma_f32_16x16x32_bf16(a0, bf[nt], acc[0][nt], 0, 0, 0);
      acc[1][nt] = __builtin_amdgcn_mfma_f32_16x16x32_bf16(a1, bf[nt], acc[1][nt], 0, 0, 0);
    }
  }
  if constexpr (DOTS == 1){
    #pragma unroll
    for (int mt = 0; mt < 2; mt++){
      #pragma unroll
      for (int i = 0; i < 4; i++){
        float ps = 0.f, pd = 0.f;
        #pragma unroll
        for (int nt = 0; nt < 8; nt++){
          float av = acc[mt][nt][i];
          int col = nt*16 + lr;
          ps = fmaf(av, va[col], ps);
          pd = fmaf(av, vb[col], pd);
        }
        ps = grp_sum16(ps); pd = grp_sum16(pd);
        int r = row0 + w*32 + mt*16 + lk*4 + i;
        if (lr == 0 && r < nrows){ sOut[r] = ps; dOut[r] = pd; }
      }
    }
  }
  if constexpr (DOTS == 2){
    #pragma unroll
    for (int mt = 0; mt < 2; mt++){
      #pragma unroll
      for (int i = 0; i < 4; i++){
        float pmu = 0.f, pdm = 0.f, pls = 0.f, pdl = 0.f;
        #pragma unroll
        for (int nt = 0; nt < 8; nt++){
          float av = acc[mt][nt][i];
          int col = nt*16 + lr;
          int c = col >> 1;
          if (col & 1){ pls = fmaf(av, vc[c], pls); pdl = fmaf(av, vd[c], pdl); }
          else        { pmu = fmaf(av, va[c], pmu); pdm = fmaf(av, vb[c], pdm); }
        }
        pmu = grp_sum16(pmu); pdm = grp_sum16(pdm);
        pls = grp_sum16(pls); pdl = grp_sum16(pdl);
        int r = row0 + w*32 + mt*16 + lk*4 + i;
        if (lr == 0 && r < nrows){
          ((float2*)sOut)[r] = make_float2(pmu, pls);
          ((float2*)dOut)[r] = make_float2(pdm, pdl);
        }
      }
    }
  }
  #pragma unroll
  for (int mt = 0; mt < 2; mt++){
    int gr0 = row0 + w*32 + mt*16 + lk*4;
    #pragma unroll
    for (int nt = 0; nt < 8; nt++){
      int col = nt*16 + lr;
      float bv = (OUT >= 1) ? bias[col] : 0.f;
      #pragma unroll
      for (int i = 0; i < 4; i++){
        int r = gr0 + i;
        if (r < nrows){
          float o = acc[mt][nt][i] + bv;
          if constexpr (OUT == 1) ((float*)Y)[(size_t)r*128 + col] = o;
          else ((unsigned short*)Y)[(size_t)r*128 + col] = f2bf(o);
        }
      }
    }
  }
}

// ---- conv aggregation: 32-lane groups, dynamic ticket (TBATCH nodes/grab), 8-deep gather ----
template<bool HAS_EW>
__global__ __launch_bounds__(256) void agg_conv(const unsigned short* __restrict__ Hb,
                                                const float* __restrict__ s,
                                                const float* __restrict__ dsc,
                                                const float* __restrict__ ewp,
                                                const int* __restrict__ rowptr,
                                                const unsigned* __restrict__ csr_u,
                                                const float* __restrict__ bias,
                                                const unsigned short* __restrict__ residb,
                                                unsigned short* __restrict__ out,
                                                unsigned* __restrict__ ctr){
  int lig = threadIdx.x & 31;
  int c0 = lig*4;
  float4 bv = *(const float4*)(bias + c0);
  for (;;){
    unsigned nb = 0;
    if (lig == 0) nb = atomicAdd(ctr, TBATCH);
    nb = __shfl((int)nb, 0, 32);
    if (nb >= NN) break;
    int vend = nb + TBATCH; if (vend > NN) vend = NN;
    for (int v = (int)nb; v < vend; v++){
      int rs = rowptr[v], re = rowptr[v+1];
      int deg = re - rs;
      float d_v = dsc[v];
      float acc[4] = {0.f,0.f,0.f,0.f};
      float pl = 0.f, ewl = 0.f;
      for (int base = rs; base < re; base += 32){
        int i = base + lig;
        int u = 0; float w = 0.f;
        if (i < re){
          u = (int)csr_u[i];
          float e = HAS_EW ? ewp[i] : 0.f;
          if (HAS_EW) ewl += e;
          float a = s[u] + d_v + e;
          float l = a > 0.f ? a : 0.2f*a;
          w = __expf(l);
        }
        pl += w;
        int nv = re - base; if (nv > 32) nv = 32;
        for (int j = 0; j < nv; j += 8){
          uint2 q[8]; float wj[8];
          #pragma unroll
          for (int k = 0; k < 8; k++){
            int uk = __shfl(u, j+k, 32);
            wj[k] = __shfl(w, j+k, 32);
            q[k] = *(const uint2*)(Hb + (size_t)uk*128 + c0);
          }
          #pragma unroll
          for (int k = 0; k < 8; k++){
            acc[0] = fmaf(wj[k], __uint_as_float(q[k].x << 16), acc[0]);
            acc[1] = fmaf(wj[k], __uint_as_float(q[k].x & 0xFFFF0000u), acc[1]);
            acc[2] = fmaf(wj[k], __uint_as_float(q[k].y << 16), acc[2]);
            acc[3] = fmaf(wj[k], __uint_as_float(q[k].y & 0xFFFF0000u), acc[3]);
          }
        }
      }
      float p = grp_sum32(pl);
      float ews = HAS_EW ? grp_sum32(ewl) : 0.f;
      float selfa = s[v] + d_v + (HAS_EW ? ews / (float)(deg > 1 ? deg : 1) : 0.f);
      float lself = selfa > 0.f ? selfa : 0.2f*selfa;
      float wself = __expf(lself);
      p += wself;
      {
        uint2 q = *(const uint2*)(Hb + (size_t)v*128 + c0);
        acc[0] = fmaf(wself, __uint_as_float(q.x << 16), acc[0]);
        acc[1] = fmaf(wself, __uint_as_float(q.x & 0xFFFF0000u), acc[1]);
        acc[2] = fmaf(wself, __uint_as_float(q.y << 16), acc[2]);
        acc[3] = fmaf(wself, __uint_as_float(q.y & 0xFFFF0000u), acc[3]);
      }
      float inv = 1.f / p;
      float o0 = fmaxf(acc[0]*inv + bv.x, 0.f);
      float o1 = fmaxf(acc[1]*inv + bv.y, 0.f);
      float o2 = fmaxf(acc[2]*inv + bv.z, 0.f);
      float o3 = fmaxf(acc[3]*inv + bv.w, 0.f);
      if (HAS_EW){
        uint2 r = *(const uint2*)(residb + (size_t)v*128 + c0);
        o0 += __uint_as_float(r.x << 16);
        o1 += __uint_as_float(r.x & 0xFFFF0000u);
        o2 += __uint_as_float(r.y << 16);
        o3 += __uint_as_float(r.y & 0xFFFF0000u);
      }
      uint2 ow;
      ow.x = (unsigned)f2bf(o0) | ((unsigned)f2bf(o1) << 16);
      ow.y = (unsigned)f2bf(o2) | ((unsigned)f2bf(o3) << 16);
      *(uint2*)(out + (size_t)v*128 + c0) = ow;
    }
  }
}

// ---- fused mu+ls aggregation: 32-lane groups, dynamic ticket, interleaved Y ----
__global__ __launch_bounds__(256) void agg_muls(const unsigned short* __restrict__ Yb,
                                                const float2* __restrict__ sg,
                                                const float2* __restrict__ dg,
                                                const float2* __restrict__ ewpmuls,
                                                const int* __restrict__ rowptr,
                                                const unsigned* __restrict__ csr_u,
                                                const float* __restrict__ bmu,
                                                const float* __restrict__ bls,
                                                float* __restrict__ outmu,
                                                float* __restrict__ outls,
                                                unsigned* __restrict__ ctr){
  int lig = threadIdx.x & 31;
  int c0 = lig*2;
  float2 bmv = make_float2(bmu[c0], bmu[c0+1]);
  float2 blv = make_float2(bls[c0], bls[c0+1]);
  for (;;){
    unsigned nb = 0;
    if (lig == 0) nb = atomicAdd(ctr, TBATCH);
    nb = __shfl((int)nb, 0, 32);
    if (nb >= NN) break;
    int vend = nb + TBATCH; if (vend > NN) vend = NN;
    for (int v = (int)nb; v < vend; v++){
      int rs = rowptr[v], re = rowptr[v+1];
      int deg = re - rs;
      float2 dv = dg[v];
      float accmu[2] = {0.f,0.f}, accls[2] = {0.f,0.f};
      float pmu = 0.f, pls = 0.f, ewlmu = 0.f, ewlls = 0.f;
      for (int base = rs; base < re; base += 32){
        int i = base + lig;
        int u = 0; float wmu = 0.f, wls = 0.f;
        if (i < re){
          u = (int)csr_u[i];
          float2 su = sg[u];
          float2 ee = ewpmuls[i];
          ewlmu += ee.x; ewlls += ee.y;
          float amu = su.x + dv.x + ee.x;
          float als = su.y + dv.y + ee.y;
          float lmu = amu > 0.f ? amu : 0.2f*amu;
          float lls = als > 0.f ? als : 0.2f*als;
          wmu = __expf(lmu); wls = __expf(lls);
        }
        pmu += wmu; pls += wls;
        int nv = re - base; if (nv > 32) nv = 32;
        for (int j = 0; j < nv; j += 8){
          uint2 q[8]; float wm[8], wl[8];
          #pragma unroll
          for (int k = 0; k < 8; k++){
            int uk = __shfl(u, j+k, 32);
            wm[k] = __shfl(wmu, j+k, 32);
            wl[k] = __shfl(wls, j+k, 32);
            q[k] = *(const uint2*)(Yb + (size_t)uk*128 + lig*4);
          }
          #pragma unroll
          for (int k = 0; k < 8; k++){
            accmu[0] = fmaf(wm[k], __uint_as_float(q[k].x << 16), accmu[0]);
            accls[0] = fmaf(wl[k], __uint_as_float(q[k].x & 0xFFFF0000u), accls[0]);
            accmu[1] = fmaf(wm[k], __uint_as_float(q[k].y << 16), accmu[1]);
            accls[1] = fmaf(wl[k], __uint_as_float(q[k].y & 0xFFFF0000u), accls[1]);
          }
        }
      }
      float Pmu = grp_sum32(pmu), Pls = grp_sum32(pls);
      float Emu = grp_sum32(ewlmu), Els = grp_sum32(ewlls);
      float2 sv = sg[v];
      float dnm = (float)(deg > 1 ? deg : 1);
      float selfmu = sv.x + dv.x + Emu/dnm;
      float selfls = sv.y + dv.y + Els/dnm;
      float lmu = selfmu > 0.f ? selfmu : 0.2f*selfmu;
      float lls = selfls > 0.f ? selfls : 0.2f*selfls;
      float wmu_s = __expf(lmu), wls_s = __expf(lls);
      Pmu += wmu_s; Pls += wls_s;
      {
        uint2 q = *(const uint2*)(Yb + (size_t)v*128 + lig*4);
        accmu[0] = fmaf(wmu_s, __uint_as_float(q.x << 16), accmu[0]);
        accls[0] = fmaf(wls_s, __uint_as_float(q.x & 0xFFFF0000u), accls[0]);
        accmu[1] = fmaf(wmu_s, __uint_as_float(q.y << 16), accmu[1]);
        accls[1] = fmaf(wls_s, __uint_as_float(q.y & 0xFFFF0000u), accls[1]);
      }
      float imu = 1.f/Pmu, ils = 1.f/Pls;
      float2 omu = make_float2(accmu[0]*imu + bmv.x, accmu[1]*imu + bmv.y);
      float2 ols = make_float2(accls[0]*ils + blv.x, accls[1]*ils + blv.y);
      *(float2*)(outmu + (size_t)v*64 + c0) = omu;
      *(float2*)(outls + (size_t)v*64 + c0) = ols;
    }
  }
}

extern "C" void kernel_launch(void* const* d_in, const int* in_sizes, int n_in,
                              void* d_out, int out_size, void* d_ws, size_t ws_size,
                              hipStream_t stream){
  const float* x    = (const float*)d_in[0];
  const int*   ei   = (const int*)  d_in[1];
  const float* ea   = (const float*)d_in[2];
  const float* W1   = (const float*)d_in[3];
  const float* a1s  = (const float*)d_in[4];
  const float* a1d  = (const float*)d_in[5];
  const float* b1   = (const float*)d_in[6];
  const float* W2   = (const float*)d_in[7];
  const float* a2s  = (const float*)d_in[8];
  const float* a2d  = (const float*)d_in[9];
  const float* b2   = (const float*)d_in[10];
  const float* We2  = (const float*)d_in[11];
  const float* ae2  = (const float*)d_in[12];
  const float* Wr   = (const float*)d_in[13];
  const float* br   = (const float*)d_in[14];
  const float* Wmu  = (const float*)d_in[15];
  const float* amus = (const float*)d_in[16];
  const float* amud = (const float*)d_in[17];
  const float* bmu  = (const float*)d_in[18];
  const float* Wemu = (const float*)d_in[19];
  const float* aemu = (const float*)d_in[20];
  const float* Wls  = (const float*)d_in[21];
  const float* alss = (const float*)d_in[22];
  const float* alsd = (const float*)d_in[23];
  const float* bls  = (const float*)d_in[24];
  const float* Wels = (const float*)d_in[25];
  const float* aels = (const float*)d_in[26];

  char* base = (char*)d_ws;
  size_t off = 0;
  auto alloc = [&](size_t bytes)->char*{
    char* p = base + off;
    off = (off + bytes + 511) & ~(size_t)511;
    return p;
  };
  int*      rowptr = (int*)   alloc((size_t)(NN+1)*4);
  unsigned* gbcnt  = (unsigned*)alloc(520*4);        // gbcnt[256] + gbfill[256] + 4 tickets
  unsigned* gbfill = gbcnt + 256;
  unsigned* tick   = gbcnt + 512;
  unsigned* gbbase = (unsigned*)alloc(257*4);
  uint2*    bdu    = (uint2*) alloc((size_t)NE*8);
  float4*   bw     = (float4*)alloc((size_t)NE*16);
  unsigned* csr_u  = (unsigned*)alloc((size_t)NE*4);
  float*    ewp2   = (float*) alloc((size_t)NE*4);
  float2*   ewpmls = (float2*)alloc((size_t)NE*8);
  float*    wv     = (float*) alloc(48*4);
  float*    s1     = (float*) alloc((size_t)NN*4);
  float*    d1     = (float*) alloc((size_t)NN*4);
  float2*   sg2    = (float2*)alloc((size_t)NN*8);
  float2*   dg2    = (float2*)alloc((size_t)NN*8);
  unsigned short* W1t  = (unsigned short*)alloc(128*128*2);
  unsigned short* W2t  = (unsigned short*)alloc(128*128*2);
  unsigned short* Wrt  = (unsigned short*)alloc(128*128*2);
  unsigned short* Wmlt = (unsigned short*)alloc(128*128*2);
  unsigned short* Xb   = (unsigned short*)alloc((size_t)NN*128*2);
  unsigned short* XRb  = (unsigned short*)alloc((size_t)NN*128*2);  // residual bf16
  unsigned short* bufA = (unsigned short*)alloc((size_t)NN*128*2);  // H1 -> H2 -> Y(muls)
  unsigned short* bufB = (unsigned short*)alloc((size_t)NN*128*2);  // h1 -> h
  if (off > ws_size) return;

  float* outF = (float*)d_out;   // [mu | logstd]
  float* muO  = outF;
  float* lsO  = outF + (size_t)NN*64;

  const int HB   = (NE + 4095)/4096;    // 1024-thread, 4 edges/thread
  const int PGB  = 2048;                // persistent agg grid: 8192 waves = machine capacity
  const int GB   = (NN + 127)/128;
  const int CB   = (NN*128/8 + 255)/256;

  // precompute + graph build
  prep_w_kernel<<<4, 256, 0, stream>>>(W1, W2, Wr, Wmu, Wls, W1t, W2t, Wrt, Wmlt);
  wvec_kernel<<<1, 64, 0, stream>>>(We2, ae2, Wemu, aemu, Wels, aels, wv);
  cast_x_kernel<<<CB, 256, 0, stream>>>(x, Xb);
  zero_kernel<<<3, 256, 0, stream>>>((int*)gbcnt, 520);
  ehist_kernel<<<HB, 1024, 0, stream>>>(ei, gbcnt);
  bscan_kernel<<<1, 256, 0, stream>>>(gbcnt, gbbase, rowptr);
  bin_kernel<<<HB, 1024, 0, stream>>>(ei, ea, wv, gbbase, gbfill, bdu, bw);
  place_kernel<<<NBUK, 1024, 0, stream>>>(bdu, bw, gbbase, rowptr, csr_u, ewp2, ewpmls);

  // conv1 (dots fused into GEMM epilogue)
  gemm_bf16<0,1><<<GB, 256, 0, stream>>>(Xb, W1t, bufA, nullptr, NN,
                                         a1s, a1d, nullptr, nullptr, s1, d1);     // H1
  agg_conv<false><<<PGB, 256, 0, stream>>>(bufA, s1, d1, nullptr, rowptr, csr_u,
                                           b1, nullptr, bufB, tick+0);            // h1
  // conv2 + residual (XR in bf16)
  gemm_bf16<0,1><<<GB, 256, 0, stream>>>(bufB, W2t, bufA, nullptr, NN,
                                         a2s, a2d, nullptr, nullptr, s1, d1);     // H2
  gemm_bf16<2,0><<<GB, 256, 0, stream>>>(Xb, Wrt, XRb, br, NN,
                                         nullptr, nullptr, nullptr, nullptr,
                                         nullptr, nullptr);                       // XR bf16
  agg_conv<true><<<PGB, 256, 0, stream>>>(bufA, s1, d1, ewp2, rowptr, csr_u,
                                          b2, XRb, bufB, tick+1);                 // h
  // mu + logstd (fused, interleaved; dots fused into GEMM)
  gemm_bf16<0,2><<<GB, 256, 0, stream>>>(bufB, Wmlt, bufA, nullptr, NN,
                                         amus, amud, alss, alsd,
                                         (float*)sg2, (float*)dg2);               // Y interleaved
  agg_muls<<<PGB, 256, 0, stream>>>(bufA, sg2, dg2, ewpmls, rowptr, csr_u,
                                    bmu, bls, muO, lsO, tick+2);
}

// Round 10
// 486.844 us; speedup vs baseline: 2.1577x; 2.1577x over previous
//
#include <hip/hip_runtime.h>

#define NN 100000
#define NE 1600000
#define BSH 9
#define NBUK 196          // ceil(NN / 512)
#define NG 32768          // edge-balanced groups (~49 edges each)

typedef __attribute__((ext_vector_type(8))) short bf16x8;
typedef __attribute__((ext_vector_type(4))) float f32x4;

__device__ __forceinline__ float grp_sum16(float v){
  #pragma unroll
  for (int o = 8; o; o >>= 1) v += __shfl_xor(v, o, 16);
  return v;
}
__device__ __forceinline__ float grp_sum32(float v){
  #pragma unroll
  for (int o = 16; o; o >>= 1) v += __shfl_xor(v, o, 32);
  return v;
}
__device__ __forceinline__ float bf2f(unsigned short x){
  return __uint_as_float(((unsigned)x) << 16);
}
__device__ __forceinline__ unsigned short f2bf(float f){
  unsigned u = __float_as_uint(f);
  return (unsigned short)((u + 0x7FFFu + ((u >> 16) & 1u)) >> 16);
}

// ---- weight prep: transpose + bf16. Wmlt interleaved: col 2c=Wmu[:,c], 2c+1=Wls[:,c] ----
__global__ void prep_w_kernel(const float* __restrict__ W1, const float* __restrict__ W2,
                              const float* __restrict__ Wr, const float* __restrict__ Wmu,
                              const float* __restrict__ Wls,
                              unsigned short* __restrict__ W1t, unsigned short* __restrict__ W2t,
                              unsigned short* __restrict__ Wrt, unsigned short* __restrict__ Wmlt){
  int b = blockIdx.x, t = threadIdx.x;
  for (int it = 0; it < 64; it++){
    int idx = it*256 + t;          // 16384 entries
    int k = idx >> 7, c = idx & 127;
    float v; unsigned short* dst;
    if (b == 0){ v = W1[k*128+c]; dst = W1t; }
    else if (b == 1){ v = W2[k*128+c]; dst = W2t; }
    else if (b == 2){ v = Wr[k*128+c]; dst = Wrt; }
    else { v = (c & 1) ? Wls[k*64 + (c>>1)] : Wmu[k*64 + (c>>1)]; dst = Wmlt; }
    dst[c*128 + k] = f2bf(v);      // [col][k]
  }
}

__global__ void wvec_kernel(const float* __restrict__ We2, const float* __restrict__ ae2,
                            const float* __restrict__ Wemu, const float* __restrict__ aemu,
                            const float* __restrict__ Wels, const float* __restrict__ aels,
                            float* __restrict__ wv){
  int t = threadIdx.x;
  if (t < 16){
    float s = 0.f; for (int c = 0; c < 128; c++) s += We2[t*128+c]*ae2[c];
    wv[t] = s;
  } else if (t < 32){
    int k = t-16; float s = 0.f; for (int c = 0; c < 64; c++) s += Wemu[k*64+c]*aemu[c];
    wv[16+k] = s;
  } else if (t < 48){
    int k = t-32; float s = 0.f; for (int c = 0; c < 64; c++) s += Wels[k*64+c]*aels[c];
    wv[32+k] = s;
  }
}

__global__ void cast_x_kernel(const float* __restrict__ x, unsigned short* __restrict__ Xb){
  int i = blockIdx.x*256 + threadIdx.x;   // 8 elems each
  if (i >= NN*128/8) return;
  const float4* src = (const float4*)x + (size_t)i*2;
  float4 v0 = src[0], v1 = src[1];
  ushort4 o0 = make_ushort4(f2bf(v0.x), f2bf(v0.y), f2bf(v0.z), f2bf(v0.w));
  ushort4 o1 = make_ushort4(f2bf(v1.x), f2bf(v1.y), f2bf(v1.z), f2bf(v1.w));
  *(ushort4*)(Xb + (size_t)i*8)     = o0;
  *(ushort4*)(Xb + (size_t)i*8 + 4) = o1;
}

__global__ void zero_kernel(int* __restrict__ p, int n){
  int i = blockIdx.x*256 + threadIdx.x;
  if (i < n) p[i] = 0;
}

// ---- coarse 256-bucket histogram of dst>>9 (LDS aggregated) ----
__global__ __launch_bounds__(1024) void ehist_kernel(const int* __restrict__ ei,
                                                     unsigned* __restrict__ gbcnt){
  __shared__ unsigned h[256];
  int t = threadIdx.x;
  if (t < 256) h[t] = 0;
  __syncthreads();
  int e0 = blockIdx.x*4096 + t;
  #pragma unroll
  for (int k = 0; k < 4; k++){
    int e = e0 + k*1024;
    if (e < NE) atomicAdd(&h[ei[NE+e] >> BSH], 1);
  }
  __syncthreads();
  if (t < 256 && h[t]) atomicAdd(&gbcnt[t], h[t]);
}

__global__ void bscan_kernel(const unsigned* __restrict__ gbcnt,
                             unsigned* __restrict__ gbbase, int* __restrict__ rowptr){
  __shared__ unsigned sh[256];
  int t = threadIdx.x;   // 256
  unsigned v = gbcnt[t];
  sh[t] = v; __syncthreads();
  for (int o = 1; o < 256; o <<= 1){
    unsigned add = (t >= o) ? sh[t-o] : 0;
    __syncthreads();
    sh[t] += add;
    __syncthreads();
  }
  gbbase[t+1] = sh[t];
  if (t == 0){ gbbase[0] = 0; rowptr[NN] = NE; }
}

// ---- bin (+fused edge-scalar dots): append {dst,u} + {s2,smu,sls} per bucket ----
__global__ __launch_bounds__(1024) void bin_kernel(const int* __restrict__ ei,
                                                   const float* __restrict__ ea,
                                                   const float* __restrict__ wv,
                                                   const unsigned* __restrict__ gbbase,
                                                   unsigned* __restrict__ gbfill,
                                                   uint2* __restrict__ bdu,
                                                   float4* __restrict__ bw){
  __shared__ unsigned hcnt[256], hbase[256], hcur[256];
  __shared__ float wvs[48];
  int t = threadIdx.x;
  if (t < 256){ hcnt[t] = 0; hcur[t] = 0; }
  else if (t >= 256 && t < 304) wvs[t-256] = wv[t-256];
  __syncthreads();
  int d[4], u[4], b[4]; float4 w[4]; bool val[4];
  int e0 = blockIdx.x*4096 + t;
  #pragma unroll
  for (int k = 0; k < 4; k++){
    int e = e0 + k*1024;
    val[k] = e < NE;
    if (val[k]){
      d[k] = ei[NE+e]; u[k] = ei[e];
      b[k] = d[k] >> BSH;
      atomicAdd(&hcnt[b[k]], 1);
      const float4* p = (const float4*)(ea + (size_t)e*16);
      float a[16]; float4 vv;
      vv = p[0]; a[0]=vv.x; a[1]=vv.y; a[2]=vv.z; a[3]=vv.w;
      vv = p[1]; a[4]=vv.x; a[5]=vv.y; a[6]=vv.z; a[7]=vv.w;
      vv = p[2]; a[8]=vv.x; a[9]=vv.y; a[10]=vv.z; a[11]=vv.w;
      vv = p[3]; a[12]=vv.x; a[13]=vv.y; a[14]=vv.z; a[15]=vv.w;
      float s2 = 0.f, smu = 0.f, sls = 0.f;
      #pragma unroll
      for (int q = 0; q < 16; q++){
        s2  = fmaf(a[q], wvs[q],    s2);
        smu = fmaf(a[q], wvs[16+q], smu);
        sls = fmaf(a[q], wvs[32+q], sls);
      }
      w[k] = make_float4(s2, smu, sls, 0.f);
    }
  }
  __syncthreads();
  if (t < 256){
    unsigned c = hcnt[t];
    hbase[t] = c ? atomicAdd(&gbfill[t], c) : 0u;
  }
  __syncthreads();
  #pragma unroll
  for (int k = 0; k < 4; k++){
    if (val[k]){
      unsigned pos = atomicAdd(&hcur[b[k]], 1);
      unsigned slot = gbbase[b[k]] + hbase[b[k]] + pos;
      bdu[slot] = make_uint2((unsigned)d[k], (unsigned)u[k]);
      bw[slot]  = w[k];
    }
  }
}

// ---- place: per-bucket sub-rowptr in LDS + scatter into L2-resident CSR region ----
__global__ __launch_bounds__(1024) void place_kernel(const uint2* __restrict__ bdu,
                                                     const float4* __restrict__ bw,
                                                     const unsigned* __restrict__ gbbase,
                                                     int* __restrict__ rowptr,
                                                     unsigned* __restrict__ csr_u,
                                                     float* __restrict__ ewp2,
                                                     float2* __restrict__ ewpmuls){
  __shared__ unsigned h[512], incl[512], cur[512];
  int b = blockIdx.x, t = threadIdx.x;
  unsigned cbase = gbbase[b];
  unsigned cnt = gbbase[b+1] - cbase;
  if (t < 512) h[t] = 0;
  __syncthreads();
  for (unsigned i = t; i < cnt; i += 1024)
    atomicAdd(&h[bdu[cbase+i].x & 511], 1);
  __syncthreads();
  if (t < 512) incl[t] = h[t];
  __syncthreads();
  for (int o = 1; o < 512; o <<= 1){
    unsigned add = (t >= o && t < 512) ? incl[t-o] : 0;
    __syncthreads();
    if (t < 512) incl[t] += add;
    __syncthreads();
  }
  if (t < 512){
    cur[t] = 0;
    int node = (b << BSH) + t;
    if (node < NN) rowptr[node] = (int)(cbase + incl[t] - h[t]);
  }
  __syncthreads();
  for (unsigned i = t; i < cnt; i += 1024){
    uint2 du = bdu[cbase+i];
    unsigned ld = du.x & 511;
    unsigned pos = atomicAdd(&cur[ld], 1);
    unsigned slot = cbase + (incl[ld] - h[ld]) + pos;
    float4 w = bw[cbase+i];
    csr_u[slot] = du.y;
    ewp2[slot] = w.x;
    ewpmuls[slot] = make_float2(w.y, w.z);
  }
}

// ---- edge-balanced group starts: gstart[g] = first node of group g ----
__global__ void lb_kernel(const int* __restrict__ rowptr, int* __restrict__ gstart){
  int g = blockIdx.x*256 + threadIdx.x;
  if (g > NG) return;
  if (g == 0){ gstart[0] = 0; return; }
  if (g == NG){ gstart[NG] = NN; return; }
  long target = ((long)g * NE) / NG;
  int lo = 0, hi = NN - 1;
  while (lo < hi){
    int mid = (lo + hi + 1) >> 1;
    if ((long)rowptr[mid] <= target) lo = mid; else hi = mid - 1;
  }
  gstart[g] = lo;
}

// ---- MFMA GEMM: Y[nrows x 128] = Xb @ Wt^T, bf16 in, fp32 acc.
//      OUT: 0=bf16, 1=f32+bias, 2=bf16+bias. DOTS: 0 none, 1 conv s/d, 2 mu/ls. ----
template<int OUT, int DOTS>
__global__ __launch_bounds__(256) void gemm_bf16(const unsigned short* __restrict__ Xb,
                                                 const unsigned short* __restrict__ Wt,
                                                 void* __restrict__ Y,
                                                 const float* __restrict__ bias, int nrows,
                                                 const float* __restrict__ va,
                                                 const float* __restrict__ vb,
                                                 const float* __restrict__ vc,
                                                 const float* __restrict__ vd,
                                                 float* __restrict__ sOut,
                                                 float* __restrict__ dOut){
  __shared__ uint4 As[128*16];   // 32 KB, XOR-swizzled chunks
  __shared__ uint4 Bs[128*16];   // 32 KB
  int t = threadIdx.x;
  int row0 = blockIdx.x * 128;
  #pragma unroll
  for (int p = 0; p < 8; p++){
    int idx = p*256 + t;
    int r = idx >> 4, cir = idx & 15;
    uint4 v = make_uint4(0,0,0,0);
    if (row0 + r < nrows) v = *(const uint4*)(Xb + ((size_t)(row0+r))*128 + cir*8);
    As[r*16 + (cir ^ (r & 7))] = v;
  }
  #pragma unroll
  for (int p = 0; p < 8; p++){
    int idx = p*256 + t;
    int r = idx >> 4, cir = idx & 15;
    Bs[r*16 + (cir ^ (r & 7))] = *(const uint4*)(Wt + (size_t)r*128 + cir*8);
  }
  __syncthreads();
  int w = t >> 6, l = t & 63;
  int lr = l & 15;
  int lk = l >> 4;
  const bf16x8* As8 = (const bf16x8*)As;
  const bf16x8* Bs8 = (const bf16x8*)Bs;
  f32x4 acc[2][8];
  f32x4 zero = {0.f, 0.f, 0.f, 0.f};
  #pragma unroll
  for (int m = 0; m < 2; m++)
    #pragma unroll
    for (int n = 0; n < 8; n++) acc[m][n] = zero;
  #pragma unroll
  for (int ks = 0; ks < 4; ks++){
    bf16x8 a0, a1, bf[8];
    { int r = w*32 + lr;      a0 = As8[r*16 + ((ks*4+lk) ^ (r&7))]; }
    { int r = w*32 + 16 + lr; a1 = As8[r*16 + ((ks*4+lk) ^ (r&7))]; }
    #pragma unroll
    for (int nt = 0; nt < 8; nt++){
      int r = nt*16 + lr;
      bf[nt] = Bs8[r*16 + ((ks*4+lk) ^ (r&7))];
    }
    #pragma unroll
    for (int nt = 0; nt < 8; nt++){
      acc[0][nt] = __builtin_amdgcn_mfma_f32_16x16x32_bf16(a0, bf[nt], acc[0][nt], 0, 0, 0);
      acc[1][nt] = __builtin_amdgcn_mfma_f32_16x16x32_bf16(a1, bf[nt], acc[1][nt], 0, 0, 0);
    }
  }
  if constexpr (DOTS == 1){
    #pragma unroll
    for (int mt = 0; mt < 2; mt++){
      #pragma unroll
      for (int i = 0; i < 4; i++){
        float ps = 0.f, pd = 0.f;
        #pragma unroll
        for (int nt = 0; nt < 8; nt++){
          float av = acc[mt][nt][i];
          int col = nt*16 + lr;
          ps = fmaf(av, va[col], ps);
          pd = fmaf(av, vb[col], pd);
        }
        ps = grp_sum16(ps); pd = grp_sum16(pd);
        int r = row0 + w*32 + mt*16 + lk*4 + i;
        if (lr == 0 && r < nrows){ sOut[r] = ps; dOut[r] = pd; }
      }
    }
  }
  if constexpr (DOTS == 2){
    #pragma unroll
    for (int mt = 0; mt < 2; mt++){
      #pragma unroll
      for (int i = 0; i < 4; i++){
        float pmu = 0.f, pdm = 0.f, pls = 0.f, pdl = 0.f;
        #pragma unroll
        for (int nt = 0; nt < 8; nt++){
          float av = acc[mt][nt][i];
          int col = nt*16 + lr;
          int c = col >> 1;
          if (col & 1){ pls = fmaf(av, vc[c], pls); pdl = fmaf(av, vd[c], pdl); }
          else        { pmu = fmaf(av, va[c], pmu); pdm = fmaf(av, vb[c], pdm); }
        }
        pmu = grp_sum16(pmu); pdm = grp_sum16(pdm);
        pls = grp_sum16(pls); pdl = grp_sum16(pdl);
        int r = row0 + w*32 + mt*16 + lk*4 + i;
        if (lr == 0 && r < nrows){
          ((float2*)sOut)[r] = make_float2(pmu, pls);
          ((float2*)dOut)[r] = make_float2(pdm, pdl);
        }
      }
    }
  }
  #pragma unroll
  for (int mt = 0; mt < 2; mt++){
    int gr0 = row0 + w*32 + mt*16 + lk*4;
    #pragma unroll
    for (int nt = 0; nt < 8; nt++){
      int col = nt*16 + lr;
      float bv = (OUT >= 1) ? bias[col] : 0.f;
      #pragma unroll
      for (int i = 0; i < 4; i++){
        int r = gr0 + i;
        if (r < nrows){
          float o = acc[mt][nt][i] + bv;
          if constexpr (OUT == 1) ((float*)Y)[(size_t)r*128 + col] = o;
          else ((unsigned short*)Y)[(size_t)r*128 + col] = f2bf(o);
        }
      }
    }
  }
}

// ---- conv aggregation: 32-lane groups, edge-balanced node ranges, 8-deep gather ----
template<bool HAS_EW>
__global__ __launch_bounds__(256) void agg_conv(const unsigned short* __restrict__ Hb,
                                                const float* __restrict__ s,
                                                const float* __restrict__ dsc,
                                                const float* __restrict__ ewp,
                                                const int* __restrict__ rowptr,
                                                const unsigned* __restrict__ csr_u,
                                                const int* __restrict__ gstart,
                                                const float* __restrict__ bias,
                                                const unsigned short* __restrict__ residb,
                                                unsigned short* __restrict__ out){
  int g = (blockIdx.x * blockDim.x + threadIdx.x) >> 5;
  int lig = threadIdx.x & 31;
  if (g >= NG) return;
  int v0 = gstart[g], v1 = gstart[g+1];
  int c0 = lig*4;
  float4 bv = *(const float4*)(bias + c0);
  for (int v = v0; v < v1; v++){
    int rs = rowptr[v], re = rowptr[v+1];
    int deg = re - rs;
    float d_v = dsc[v];
    float acc[4] = {0.f,0.f,0.f,0.f};
    float pl = 0.f, ewl = 0.f;
    for (int base = rs; base < re; base += 32){
      int i = base + lig;
      int u = 0; float w = 0.f;
      if (i < re){
        u = (int)csr_u[i];
        float e = HAS_EW ? ewp[i] : 0.f;
        if (HAS_EW) ewl += e;
        float a = s[u] + d_v + e;
        float l = a > 0.f ? a : 0.2f*a;
        w = __expf(l);
      }
      pl += w;
      int nv = re - base; if (nv > 32) nv = 32;
      for (int j = 0; j < nv; j += 8){
        uint2 q[8]; float wj[8];
        #pragma unroll
        for (int k = 0; k < 8; k++){
          int uk = __shfl(u, j+k, 32);
          wj[k] = __shfl(w, j+k, 32);
          q[k] = *(const uint2*)(Hb + (size_t)uk*128 + c0);
        }
        #pragma unroll
        for (int k = 0; k < 8; k++){
          acc[0] = fmaf(wj[k], __uint_as_float(q[k].x << 16), acc[0]);
          acc[1] = fmaf(wj[k], __uint_as_float(q[k].x & 0xFFFF0000u), acc[1]);
          acc[2] = fmaf(wj[k], __uint_as_float(q[k].y << 16), acc[2]);
          acc[3] = fmaf(wj[k], __uint_as_float(q[k].y & 0xFFFF0000u), acc[3]);
        }
      }
    }
    float p = grp_sum32(pl);
    float ews = HAS_EW ? grp_sum32(ewl) : 0.f;
    float selfa = s[v] + d_v + (HAS_EW ? ews / (float)(deg > 1 ? deg : 1) : 0.f);
    float lself = selfa > 0.f ? selfa : 0.2f*selfa;
    float wself = __expf(lself);
    p += wself;
    {
      uint2 q = *(const uint2*)(Hb + (size_t)v*128 + c0);
      acc[0] = fmaf(wself, __uint_as_float(q.x << 16), acc[0]);
      acc[1] = fmaf(wself, __uint_as_float(q.x & 0xFFFF0000u), acc[1]);
      acc[2] = fmaf(wself, __uint_as_float(q.y << 16), acc[2]);
      acc[3] = fmaf(wself, __uint_as_float(q.y & 0xFFFF0000u), acc[3]);
    }
    float inv = 1.f / p;
    float o0 = fmaxf(acc[0]*inv + bv.x, 0.f);
    float o1 = fmaxf(acc[1]*inv + bv.y, 0.f);
    float o2 = fmaxf(acc[2]*inv + bv.z, 0.f);
    float o3 = fmaxf(acc[3]*inv + bv.w, 0.f);
    if (HAS_EW){
      uint2 r = *(const uint2*)(residb + (size_t)v*128 + c0);
      o0 += __uint_as_float(r.x << 16);
      o1 += __uint_as_float(r.x & 0xFFFF0000u);
      o2 += __uint_as_float(r.y << 16);
      o3 += __uint_as_float(r.y & 0xFFFF0000u);
    }
    uint2 ow;
    ow.x = (unsigned)f2bf(o0) | ((unsigned)f2bf(o1) << 16);
    ow.y = (unsigned)f2bf(o2) | ((unsigned)f2bf(o3) << 16);
    *(uint2*)(out + (size_t)v*128 + c0) = ow;
  }
}

// ---- fused mu+ls aggregation: 32-lane groups, edge-balanced ranges, interleaved Y ----
__global__ __launch_bounds__(256) void agg_muls(const unsigned short* __restrict__ Yb,
                                                const float2* __restrict__ sg,
                                                const float2* __restrict__ dg,
                                                const float2* __restrict__ ewpmuls,
                                                const int* __restrict__ rowptr,
                                                const unsigned* __restrict__ csr_u,
                                                const int* __restrict__ gstart,
                                                const float* __restrict__ bmu,
                                                const float* __restrict__ bls,
                                                float* __restrict__ outmu,
                                                float* __restrict__ outls){
  int g = (blockIdx.x * blockDim.x + threadIdx.x) >> 5;
  int lig = threadIdx.x & 31;
  if (g >= NG) return;
  int v0 = gstart[g], v1 = gstart[g+1];
  int c0 = lig*2;
  float2 bmv = make_float2(bmu[c0], bmu[c0+1]);
  float2 blv = make_float2(bls[c0], bls[c0+1]);
  for (int v = v0; v < v1; v++){
    int rs = rowptr[v], re = rowptr[v+1];
    int deg = re - rs;
    float2 dv = dg[v];
    float accmu[2] = {0.f,0.f}, accls[2] = {0.f,0.f};
    float pmu = 0.f, pls = 0.f, ewlmu = 0.f, ewlls = 0.f;
    for (int base = rs; base < re; base += 32){
      int i = base + lig;
      int u = 0; float wmu = 0.f, wls = 0.f;
      if (i < re){
        u = (int)csr_u[i];
        float2 su = sg[u];
        float2 ee = ewpmuls[i];
        ewlmu += ee.x; ewlls += ee.y;
        float amu = su.x + dv.x + ee.x;
        float als = su.y + dv.y + ee.y;
        float lmu = amu > 0.f ? amu : 0.2f*amu;
        float lls = als > 0.f ? als : 0.2f*als;
        wmu = __expf(lmu); wls = __expf(lls);
      }
      pmu += wmu; pls += wls;
      int nv = re - base; if (nv > 32) nv = 32;
      for (int j = 0; j < nv; j += 8){
        uint2 q[8]; float wm[8], wl[8];
        #pragma unroll
        for (int k = 0; k < 8; k++){
          int uk = __shfl(u, j+k, 32);
          wm[k] = __shfl(wmu, j+k, 32);
          wl[k] = __shfl(wls, j+k, 32);
          q[k] = *(const uint2*)(Yb + (size_t)uk*128 + lig*4);
        }
        #pragma unroll
        for (int k = 0; k < 8; k++){
          accmu[0] = fmaf(wm[k], __uint_as_float(q[k].x << 16), accmu[0]);
          accls[0] = fmaf(wl[k], __uint_as_float(q[k].x & 0xFFFF0000u), accls[0]);
          accmu[1] = fmaf(wm[k], __uint_as_float(q[k].y << 16), accmu[1]);
          accls[1] = fmaf(wl[k], __uint_as_float(q[k].y & 0xFFFF0000u), accls[1]);
        }
      }
    }
    float Pmu = grp_sum32(pmu), Pls = grp_sum32(pls);
    float Emu = grp_sum32(ewlmu), Els = grp_sum32(ewlls);
    float2 sv = sg[v];
    float dnm = (float)(deg > 1 ? deg : 1);
    float selfmu = sv.x + dv.x + Emu/dnm;
    float selfls = sv.y + dv.y + Els/dnm;
    float lmu = selfmu > 0.f ? selfmu : 0.2f*selfmu;
    float lls = selfls > 0.f ? selfls : 0.2f*selfls;
    float wmu_s = __expf(lmu), wls_s = __expf(lls);
    Pmu += wmu_s; Pls += wls_s;
    {
      uint2 q = *(const uint2*)(Yb + (size_t)v*128 + lig*4);
      accmu[0] = fmaf(wmu_s, __uint_as_float(q.x << 16), accmu[0]);
      accls[0] = fmaf(wls_s, __uint_as_float(q.x & 0xFFFF0000u), accls[0]);
      accmu[1] = fmaf(wmu_s, __uint_as_float(q.y << 16), accmu[1]);
      accls[1] = fmaf(wls_s, __uint_as_float(q.y & 0xFFFF0000u), accls[1]);
    }
    float imu = 1.f/Pmu, ils = 1.f/Pls;
    float2 omu = make_float2(accmu[0]*imu + bmv.x, accmu[1]*imu + bmv.y);
    float2 ols = make_float2(accls[0]*ils + blv.x, accls[1]*ils + blv.y);
    *(float2*)(outmu + (size_t)v*64 + c0) = omu;
    *(float2*)(outls + (size_t)v*64 + c0) = ols;
  }
}

extern "C" void kernel_launch(void* const* d_in, const int* in_sizes, int n_in,
                              void* d_out, int out_size, void* d_ws, size_t ws_size,
                              hipStream_t stream){
  const float* x    = (const float*)d_in[0];
  const int*   ei   = (const int*)  d_in[1];
  const float* ea   = (const float*)d_in[2];
  const float* W1   = (const float*)d_in[3];
  const float* a1s  = (const float*)d_in[4];
  const float* a1d  = (const float*)d_in[5];
  const float* b1   = (const float*)d_in[6];
  const float* W2   = (const float*)d_in[7];
  const float* a2s  = (const float*)d_in[8];
  const float* a2d  = (const float*)d_in[9];
  const float* b2   = (const float*)d_in[10];
  const float* We2  = (const float*)d_in[11];
  const float* ae2  = (const float*)d_in[12];
  const float* Wr   = (const float*)d_in[13];
  const float* br   = (const float*)d_in[14];
  const float* Wmu  = (const float*)d_in[15];
  const float* amus = (const float*)d_in[16];
  const float* amud = (const float*)d_in[17];
  const float* bmu  = (const float*)d_in[18];
  const float* Wemu = (const float*)d_in[19];
  const float* aemu = (const float*)d_in[20];
  const float* Wls  = (const float*)d_in[21];
  const float* alss = (const float*)d_in[22];
  const float* alsd = (const float*)d_in[23];
  const float* bls  = (const float*)d_in[24];
  const float* Wels = (const float*)d_in[25];
  const float* aels = (const float*)d_in[26];

  char* base = (char*)d_ws;
  size_t off = 0;
  auto alloc = [&](size_t bytes)->char*{
    char* p = base + off;
    off = (off + bytes + 511) & ~(size_t)511;
    return p;
  };
  int*      rowptr = (int*)   alloc((size_t)(NN+1)*4);
  unsigned* gbcnt  = (unsigned*)alloc(512*4);        // gbcnt[256] + gbfill[256]
  unsigned* gbfill = gbcnt + 256;
  unsigned* gbbase = (unsigned*)alloc(257*4);
  int*      gstart = (int*)   alloc((size_t)(NG+1)*4);
  uint2*    bdu    = (uint2*) alloc((size_t)NE*8);
  float4*   bw     = (float4*)alloc((size_t)NE*16);
  unsigned* csr_u  = (unsigned*)alloc((size_t)NE*4);
  float*    ewp2   = (float*) alloc((size_t)NE*4);
  float2*   ewpmls = (float2*)alloc((size_t)NE*8);
  float*    wv     = (float*) alloc(48*4);
  float*    s1     = (float*) alloc((size_t)NN*4);
  float*    d1     = (float*) alloc((size_t)NN*4);
  float2*   sg2    = (float2*)alloc((size_t)NN*8);
  float2*   dg2    = (float2*)alloc((size_t)NN*8);
  unsigned short* W1t  = (unsigned short*)alloc(128*128*2);
  unsigned short* W2t  = (unsigned short*)alloc(128*128*2);
  unsigned short* Wrt  = (unsigned short*)alloc(128*128*2);
  unsigned short* Wmlt = (unsigned short*)alloc(128*128*2);
  unsigned short* Xb   = (unsigned short*)alloc((size_t)NN*128*2);
  unsigned short* XRb  = (unsigned short*)alloc((size_t)NN*128*2);  // residual bf16
  unsigned short* bufA = (unsigned short*)alloc((size_t)NN*128*2);  // H1 -> H2 -> Y(muls)
  unsigned short* bufB = (unsigned short*)alloc((size_t)NN*128*2);  // h1 -> h
  if (off > ws_size) return;

  float* outF = (float*)d_out;   // [mu | logstd]
  float* muO  = outF;
  float* lsO  = outF + (size_t)NN*64;

  const int HB   = (NE + 4095)/4096;    // 1024-thread, 4 edges/thread
  const int AGB  = (NG*32)/256;         // 4096 blocks, 8 groups each
  const int GB   = (NN + 127)/128;
  const int CB   = (NN*128/8 + 255)/256;
  const int LBB  = (NG + 1 + 255)/256;

  // precompute + graph build
  prep_w_kernel<<<4, 256, 0, stream>>>(W1, W2, Wr, Wmu, Wls, W1t, W2t, Wrt, Wmlt);
  wvec_kernel<<<1, 64, 0, stream>>>(We2, ae2, Wemu, aemu, Wels, aels, wv);
  cast_x_kernel<<<CB, 256, 0, stream>>>(x, Xb);
  zero_kernel<<<2, 256, 0, stream>>>((int*)gbcnt, 512);
  ehist_kernel<<<HB, 1024, 0, stream>>>(ei, gbcnt);
  bscan_kernel<<<1, 256, 0, stream>>>(gbcnt, gbbase, rowptr);
  bin_kernel<<<HB, 1024, 0, stream>>>(ei, ea, wv, gbbase, gbfill, bdu, bw);
  place_kernel<<<NBUK, 1024, 0, stream>>>(bdu, bw, gbbase, rowptr, csr_u, ewp2, ewpmls);
  lb_kernel<<<LBB, 256, 0, stream>>>(rowptr, gstart);

  // conv1 (dots fused into GEMM epilogue)
  gemm_bf16<0,1><<<GB, 256, 0, stream>>>(Xb, W1t, bufA, nullptr, NN,
                                         a1s, a1d, nullptr, nullptr, s1, d1);     // H1
  agg_conv<false><<<AGB, 256, 0, stream>>>(bufA, s1, d1, nullptr, rowptr, csr_u,
                                           gstart, b1, nullptr, bufB);            // h1
  // conv2 + residual (XR in bf16)
  gemm_bf16<0,1><<<GB, 256, 0, stream>>>(bufB, W2t, bufA, nullptr, NN,
                                         a2s, a2d, nullptr, nullptr, s1, d1);     // H2
  gemm_bf16<2,0><<<GB, 256, 0, stream>>>(Xb, Wrt, XRb, br, NN,
                                         nullptr, nullptr, nullptr, nullptr,
                                         nullptr, nullptr);                       // XR bf16
  agg_conv<true><<<AGB, 256, 0, stream>>>(bufA, s1, d1, ewp2, rowptr, csr_u,
                                          gstart, b2, XRb, bufB);                 // h
  // mu + logstd (fused, interleaved; dots fused into GEMM)
  gemm_bf16<0,2><<<GB, 256, 0, stream>>>(bufB, Wmlt, bufA, nullptr, NN,
                                         amus, amud, alss, alsd,
                                         (float*)sg2, (float*)dg2);               // Y interleaved
  agg_muls<<<AGB, 256, 0, stream>>>(bufA, sg2, dg2, ewpmls, rowptr, csr_u,
                                    gstart, bmu, bls, muO, lsO);
}

// Round 11
// 480.424 us; speedup vs baseline: 2.1865x; 1.0134x over previous
//
#include <hip/hip_runtime.h>

#define NN 100000
#define NE 1600000
#define BSH 9
#define NBUK 196          // ceil(NN / 512)
#define NDB 64            // degree bins for counting sort
#define NB  ((NN + 255)/256)

typedef __attribute__((ext_vector_type(8))) short bf16x8;
typedef __attribute__((ext_vector_type(4))) float f32x4;

__device__ __forceinline__ float grp_sum16(float v){
  #pragma unroll
  for (int o = 8; o; o >>= 1) v += __shfl_xor(v, o, 16);
  return v;
}
__device__ __forceinline__ float grp_sum32(float v){
  #pragma unroll
  for (int o = 16; o; o >>= 1) v += __shfl_xor(v, o, 32);
  return v;
}
__device__ __forceinline__ float bf2f(unsigned short x){
  return __uint_as_float(((unsigned)x) << 16);
}
__device__ __forceinline__ unsigned short f2bf(float f){
  unsigned u = __float_as_uint(f);
  return (unsigned short)((u + 0x7FFFu + ((u >> 16) & 1u)) >> 16);
}

// ---- weight prep: transpose + bf16. Wmlt interleaved: col 2c=Wmu[:,c], 2c+1=Wls[:,c] ----
__global__ void prep_w_kernel(const float* __restrict__ W1, const float* __restrict__ W2,
                              const float* __restrict__ Wr, const float* __restrict__ Wmu,
                              const float* __restrict__ Wls,
                              unsigned short* __restrict__ W1t, unsigned short* __restrict__ W2t,
                              unsigned short* __restrict__ Wrt, unsigned short* __restrict__ Wmlt){
  int b = blockIdx.x, t = threadIdx.x;
  for (int it = 0; it < 64; it++){
    int idx = it*256 + t;          // 16384 entries
    int k = idx >> 7, c = idx & 127;
    float v; unsigned short* dst;
    if (b == 0){ v = W1[k*128+c]; dst = W1t; }
    else if (b == 1){ v = W2[k*128+c]; dst = W2t; }
    else if (b == 2){ v = Wr[k*128+c]; dst = Wrt; }
    else { v = (c & 1) ? Wls[k*64 + (c>>1)] : Wmu[k*64 + (c>>1)]; dst = Wmlt; }
    dst[c*128 + k] = f2bf(v);      // [col][k]
  }
}

__global__ void wvec_kernel(const float* __restrict__ We2, const float* __restrict__ ae2,
                            const float* __restrict__ Wemu, const float* __restrict__ aemu,
                            const float* __restrict__ Wels, const float* __restrict__ aels,
                            float* __restrict__ wv){
  int t = threadIdx.x;
  if (t < 16){
    float s = 0.f; for (int c = 0; c < 128; c++) s += We2[t*128+c]*ae2[c];
    wv[t] = s;
  } else if (t < 32){
    int k = t-16; float s = 0.f; for (int c = 0; c < 64; c++) s += Wemu[k*64+c]*aemu[c];
    wv[16+k] = s;
  } else if (t < 48){
    int k = t-32; float s = 0.f; for (int c = 0; c < 64; c++) s += Wels[k*64+c]*aels[c];
    wv[32+k] = s;
  }
}

__global__ void cast_x_kernel(const float* __restrict__ x, unsigned short* __restrict__ Xb){
  int i = blockIdx.x*256 + threadIdx.x;   // 8 elems each
  if (i >= NN*128/8) return;
  const float4* src = (const float4*)x + (size_t)i*2;
  float4 v0 = src[0], v1 = src[1];
  ushort4 o0 = make_ushort4(f2bf(v0.x), f2bf(v0.y), f2bf(v0.z), f2bf(v0.w));
  ushort4 o1 = make_ushort4(f2bf(v1.x), f2bf(v1.y), f2bf(v1.z), f2bf(v1.w));
  *(ushort4*)(Xb + (size_t)i*8)     = o0;
  *(ushort4*)(Xb + (size_t)i*8 + 4) = o1;
}

__global__ void zero_kernel(int* __restrict__ p, int n){
  int i = blockIdx.x*256 + threadIdx.x;
  if (i < n) p[i] = 0;
}

// ---- coarse 256-bucket histogram of dst>>9 (LDS aggregated) ----
__global__ __launch_bounds__(1024) void ehist_kernel(const int* __restrict__ ei,
                                                     unsigned* __restrict__ gbcnt){
  __shared__ unsigned h[256];
  int t = threadIdx.x;
  if (t < 256) h[t] = 0;
  __syncthreads();
  int e0 = blockIdx.x*4096 + t;
  #pragma unroll
  for (int k = 0; k < 4; k++){
    int e = e0 + k*1024;
    if (e < NE) atomicAdd(&h[ei[NE+e] >> BSH], 1);
  }
  __syncthreads();
  if (t < 256 && h[t]) atomicAdd(&gbcnt[t], h[t]);
}

__global__ void bscan_kernel(const unsigned* __restrict__ gbcnt,
                             unsigned* __restrict__ gbbase, int* __restrict__ rowptr){
  __shared__ unsigned sh[256];
  int t = threadIdx.x;   // 256
  unsigned v = gbcnt[t];
  sh[t] = v; __syncthreads();
  for (int o = 1; o < 256; o <<= 1){
    unsigned add = (t >= o) ? sh[t-o] : 0;
    __syncthreads();
    sh[t] += add;
    __syncthreads();
  }
  gbbase[t+1] = sh[t];
  if (t == 0){ gbbase[0] = 0; rowptr[NN] = NE; }
}

// ---- bin (+fused edge-scalar dots): append {dst,u} + {s2,smu,sls} per bucket ----
__global__ __launch_bounds__(1024) void bin_kernel(const int* __restrict__ ei,
                                                   const float* __restrict__ ea,
                                                   const float* __restrict__ wv,
                                                   const unsigned* __restrict__ gbbase,
                                                   unsigned* __restrict__ gbfill,
                                                   uint2* __restrict__ bdu,
                                                   float4* __restrict__ bw){
  __shared__ unsigned hcnt[256], hbase[256], hcur[256];
  __shared__ float wvs[48];
  int t = threadIdx.x;
  if (t < 256){ hcnt[t] = 0; hcur[t] = 0; }
  else if (t >= 256 && t < 304) wvs[t-256] = wv[t-256];
  __syncthreads();
  int d[4], u[4], b[4]; float4 w[4]; bool val[4];
  int e0 = blockIdx.x*4096 + t;
  #pragma unroll
  for (int k = 0; k < 4; k++){
    int e = e0 + k*1024;
    val[k] = e < NE;
    if (val[k]){
      d[k] = ei[NE+e]; u[k] = ei[e];
      b[k] = d[k] >> BSH;
      atomicAdd(&hcnt[b[k]], 1);
      const float4* p = (const float4*)(ea + (size_t)e*16);
      float a[16]; float4 vv;
      vv = p[0]; a[0]=vv.x; a[1]=vv.y; a[2]=vv.z; a[3]=vv.w;
      vv = p[1]; a[4]=vv.x; a[5]=vv.y; a[6]=vv.z; a[7]=vv.w;
      vv = p[2]; a[8]=vv.x; a[9]=vv.y; a[10]=vv.z; a[11]=vv.w;
      vv = p[3]; a[12]=vv.x; a[13]=vv.y; a[14]=vv.z; a[15]=vv.w;
      float s2 = 0.f, smu = 0.f, sls = 0.f;
      #pragma unroll
      for (int q = 0; q < 16; q++){
        s2  = fmaf(a[q], wvs[q],    s2);
        smu = fmaf(a[q], wvs[16+q], smu);
        sls = fmaf(a[q], wvs[32+q], sls);
      }
      w[k] = make_float4(s2, smu, sls, 0.f);
    }
  }
  __syncthreads();
  if (t < 256){
    unsigned c = hcnt[t];
    hbase[t] = c ? atomicAdd(&gbfill[t], c) : 0u;
  }
  __syncthreads();
  #pragma unroll
  for (int k = 0; k < 4; k++){
    if (val[k]){
      unsigned pos = atomicAdd(&hcur[b[k]], 1);
      unsigned slot = gbbase[b[k]] + hbase[b[k]] + pos;
      bdu[slot] = make_uint2((unsigned)d[k], (unsigned)u[k]);
      bw[slot]  = w[k];
    }
  }
}

// ---- place: per-bucket sub-rowptr in LDS + scatter into L2-resident CSR region ----
__global__ __launch_bounds__(1024) void place_kernel(const uint2* __restrict__ bdu,
                                                     const float4* __restrict__ bw,
                                                     const unsigned* __restrict__ gbbase,
                                                     int* __restrict__ rowptr,
                                                     unsigned* __restrict__ csr_u,
                                                     float* __restrict__ ewp2,
                                                     float2* __restrict__ ewpmuls){
  __shared__ unsigned h[512], incl[512], cur[512];
  int b = blockIdx.x, t = threadIdx.x;
  unsigned cbase = gbbase[b];
  unsigned cnt = gbbase[b+1] - cbase;
  if (t < 512) h[t] = 0;
  __syncthreads();
  for (unsigned i = t; i < cnt; i += 1024)
    atomicAdd(&h[bdu[cbase+i].x & 511], 1);
  __syncthreads();
  if (t < 512) incl[t] = h[t];
  __syncthreads();
  for (int o = 1; o < 512; o <<= 1){
    unsigned add = (t >= o && t < 512) ? incl[t-o] : 0;
    __syncthreads();
    if (t < 512) incl[t] += add;
    __syncthreads();
  }
  if (t < 512){
    cur[t] = 0;
    int node = (b << BSH) + t;
    if (node < NN) rowptr[node] = (int)(cbase + incl[t] - h[t]);
  }
  __syncthreads();
  for (unsigned i = t; i < cnt; i += 1024){
    uint2 du = bdu[cbase+i];
    unsigned ld = du.x & 511;
    unsigned pos = atomicAdd(&cur[ld], 1);
    unsigned slot = cbase + (incl[ld] - h[ld]) + pos;
    float4 w = bw[cbase+i];
    csr_u[slot] = du.y;
    ewp2[slot] = w.x;
    ewpmuls[slot] = make_float2(w.y, w.z);
  }
}

// ---- degree counting-sort: dhist -> dscan -> dscatter => perm (nodes by degree) ----
__global__ void dhist_kernel(const int* __restrict__ rowptr, unsigned* __restrict__ dcnt){
  __shared__ unsigned h[NDB];
  int t = threadIdx.x;
  if (t < NDB) h[t] = 0;
  __syncthreads();
  int v = blockIdx.x*256 + t;
  if (v < NN){
    int d = rowptr[v+1] - rowptr[v]; if (d > NDB-1) d = NDB-1;
    atomicAdd(&h[d], 1);
  }
  __syncthreads();
  if (t < NDB && h[t]) atomicAdd(&dcnt[t], h[t]);
}

__global__ void dscan_kernel(const unsigned* __restrict__ dcnt, unsigned* __restrict__ dbase){
  __shared__ unsigned sh[NDB];
  int t = threadIdx.x;   // 64
  unsigned v = dcnt[t];
  sh[t] = v; __syncthreads();
  for (int o = 1; o < NDB; o <<= 1){
    unsigned add = (t >= o) ? sh[t-o] : 0;
    __syncthreads();
    sh[t] += add;
    __syncthreads();
  }
  dbase[t] = sh[t] - v;   // exclusive
}

__global__ void dscatter_kernel(const int* __restrict__ rowptr, const unsigned* __restrict__ dbase,
                                unsigned* __restrict__ dfill, int* __restrict__ perm){
  __shared__ unsigned hc[NDB], hb[NDB], cur[NDB];
  int t = threadIdx.x;
  if (t < NDB){ hc[t] = 0; cur[t] = 0; }
  __syncthreads();
  int v = blockIdx.x*256 + t; int d = -1;
  if (v < NN){
    d = rowptr[v+1] - rowptr[v]; if (d > NDB-1) d = NDB-1;
    atomicAdd(&hc[d], 1);
  }
  __syncthreads();
  if (t < NDB){
    unsigned c = hc[t];
    hb[t] = c ? atomicAdd(&dfill[t], c) : 0u;
  }
  __syncthreads();
  if (v < NN){
    unsigned pos = atomicAdd(&cur[d], 1);
    perm[dbase[d] + hb[d] + pos] = v;
  }
}

// ---- MFMA GEMM: Y[nrows x 128] = Xb @ Wt^T, bf16 in, fp32 acc.
//      OUT: 0=bf16, 1=f32+bias, 2=bf16+bias. DOTS: 0 none, 1 conv s/d, 2 mu/ls. ----
template<int OUT, int DOTS>
__global__ __launch_bounds__(256) void gemm_bf16(const unsigned short* __restrict__ Xb,
                                                 const unsigned short* __restrict__ Wt,
                                                 void* __restrict__ Y,
                                                 const float* __restrict__ bias, int nrows,
                                                 const float* __restrict__ va,
                                                 const float* __restrict__ vb,
                                                 const float* __restrict__ vc,
                                                 const float* __restrict__ vd,
                                                 float* __restrict__ sOut,
                                                 float* __restrict__ dOut){
  __shared__ uint4 As[128*16];   // 32 KB, XOR-swizzled chunks
  __shared__ uint4 Bs[128*16];   // 32 KB
  int t = threadIdx.x;
  int row0 = blockIdx.x * 128;
  #pragma unroll
  for (int p = 0; p < 8; p++){
    int idx = p*256 + t;
    int r = idx >> 4, cir = idx & 15;
    uint4 v = make_uint4(0,0,0,0);
    if (row0 + r < nrows) v = *(const uint4*)(Xb + ((size_t)(row0+r))*128 + cir*8);
    As[r*16 + (cir ^ (r & 7))] = v;
  }
  #pragma unroll
  for (int p = 0; p < 8; p++){
    int idx = p*256 + t;
    int r = idx >> 4, cir = idx & 15;
    Bs[r*16 + (cir ^ (r & 7))] = *(const uint4*)(Wt + (size_t)r*128 + cir*8);
  }
  __syncthreads();
  int w = t >> 6, l = t & 63;
  int lr = l & 15;
  int lk = l >> 4;
  const bf16x8* As8 = (const bf16x8*)As;
  const bf16x8* Bs8 = (const bf16x8*)Bs;
  f32x4 acc[2][8];
  f32x4 zero = {0.f, 0.f, 0.f, 0.f};
  #pragma unroll
  for (int m = 0; m < 2; m++)
    #pragma unroll
    for (int n = 0; n < 8; n++) acc[m][n] = zero;
  #pragma unroll
  for (int ks = 0; ks < 4; ks++){
    bf16x8 a0, a1, bf[8];
    { int r = w*32 + lr;      a0 = As8[r*16 + ((ks*4+lk) ^ (r&7))]; }
    { int r = w*32 + 16 + lr; a1 = As8[r*16 + ((ks*4+lk) ^ (r&7))]; }
    #pragma unroll
    for (int nt = 0; nt < 8; nt++){
      int r = nt*16 + lr;
      bf[nt] = Bs8[r*16 + ((ks*4+lk) ^ (r&7))];
    }
    #pragma unroll
    for (int nt = 0; nt < 8; nt++){
      acc[0][nt] = __builtin_amdgcn_mfma_f32_16x16x32_bf16(a0, bf[nt], acc[0][nt], 0, 0, 0);
      acc[1][nt] = __builtin_amdgcn_mfma_f32_16x16x32_bf16(a1, bf[nt], acc[1][nt], 0, 0, 0);
    }
  }
  if constexpr (DOTS == 1){
    #pragma unroll
    for (int mt = 0; mt < 2; mt++){
      #pragma unroll
      for (int i = 0; i < 4; i++){
        float ps = 0.f, pd = 0.f;
        #pragma unroll
        for (int nt = 0; nt < 8; nt++){
          float av = acc[mt][nt][i];
          int col = nt*16 + lr;
          ps = fmaf(av, va[col], ps);
          pd = fmaf(av, vb[col], pd);
        }
        ps = grp_sum16(ps); pd = grp_sum16(pd);
        int r = row0 + w*32 + mt*16 + lk*4 + i;
        if (lr == 0 && r < nrows){ sOut[r] = ps; dOut[r] = pd; }
      }
    }
  }
  if constexpr (DOTS == 2){
    #pragma unroll
    for (int mt = 0; mt < 2; mt++){
      #pragma unroll
      for (int i = 0; i < 4; i++){
        float pmu = 0.f, pdm = 0.f, pls = 0.f, pdl = 0.f;
        #pragma unroll
        for (int nt = 0; nt < 8; nt++){
          float av = acc[mt][nt][i];
          int col = nt*16 + lr;
          int c = col >> 1;
          if (col & 1){ pls = fmaf(av, vc[c], pls); pdl = fmaf(av, vd[c], pdl); }
          else        { pmu = fmaf(av, va[c], pmu); pdm = fmaf(av, vb[c], pdm); }
        }
        pmu = grp_sum16(pmu); pdm = grp_sum16(pdm);
        pls = grp_sum16(pls); pdl = grp_sum16(pdl);
        int r = row0 + w*32 + mt*16 + lk*4 + i;
        if (lr == 0 && r < nrows){
          ((float2*)sOut)[r] = make_float2(pmu, pls);
          ((float2*)dOut)[r] = make_float2(pdm, pdl);
        }
      }
    }
  }
  #pragma unroll
  for (int mt = 0; mt < 2; mt++){
    int gr0 = row0 + w*32 + mt*16 + lk*4;
    #pragma unroll
    for (int nt = 0; nt < 8; nt++){
      int col = nt*16 + lr;
      float bv = (OUT >= 1) ? bias[col] : 0.f;
      #pragma unroll
      for (int i = 0; i < 4; i++){
        int r = gr0 + i;
        if (r < nrows){
          float o = acc[mt][nt][i] + bv;
          if constexpr (OUT == 1) ((float*)Y)[(size_t)r*128 + col] = o;
          else ((unsigned short*)Y)[(size_t)r*128 + col] = f2bf(o);
        }
      }
    }
  }
}

// ---- conv aggregation: 32-lane group per node, degree-sorted via perm, 8-deep gather ----
template<bool HAS_EW>
__global__ __launch_bounds__(256) void agg_conv(const unsigned short* __restrict__ Hb,
                                                const float* __restrict__ s,
                                                const float* __restrict__ dsc,
                                                const float* __restrict__ ewp,
                                                const int* __restrict__ rowptr,
                                                const unsigned* __restrict__ csr_u,
                                                const int* __restrict__ perm,
                                                const float* __restrict__ bias,
                                                const unsigned short* __restrict__ residb,
                                                unsigned short* __restrict__ out){
  int g = (blockIdx.x * blockDim.x + threadIdx.x) >> 5;
  int lig = threadIdx.x & 31;
  if (g >= NN) return;
  int v = perm[g];
  int rs = rowptr[v], re = rowptr[v+1];
  int deg = re - rs;
  float d_v = dsc[v];
  int c0 = lig*4;
  float4 bv = *(const float4*)(bias + c0);
  float acc[4] = {0.f,0.f,0.f,0.f};
  float pl = 0.f, ewl = 0.f;
  for (int base = rs; base < re; base += 32){
    int i = base + lig;
    int u = 0; float w = 0.f;
    if (i < re){
      u = (int)csr_u[i];
      float e = HAS_EW ? ewp[i] : 0.f;
      if (HAS_EW) ewl += e;
      float a = s[u] + d_v + e;
      float l = a > 0.f ? a : 0.2f*a;
      w = __expf(l);
    }
    pl += w;
    int nv = re - base; if (nv > 32) nv = 32;
    for (int j = 0; j < nv; j += 8){
      uint2 q[8]; float wj[8];
      #pragma unroll
      for (int k = 0; k < 8; k++){
        int uk = __shfl(u, j+k, 32);
        wj[k] = __shfl(w, j+k, 32);
        q[k] = *(const uint2*)(Hb + (size_t)uk*128 + c0);
      }
      #pragma unroll
      for (int k = 0; k < 8; k++){
        acc[0] = fmaf(wj[k], __uint_as_float(q[k].x << 16), acc[0]);
        acc[1] = fmaf(wj[k], __uint_as_float(q[k].x & 0xFFFF0000u), acc[1]);
        acc[2] = fmaf(wj[k], __uint_as_float(q[k].y << 16), acc[2]);
        acc[3] = fmaf(wj[k], __uint_as_float(q[k].y & 0xFFFF0000u), acc[3]);
      }
    }
  }
  float p = grp_sum32(pl);
  float ews = HAS_EW ? grp_sum32(ewl) : 0.f;
  float selfa = s[v] + d_v + (HAS_EW ? ews / (float)(deg > 1 ? deg : 1) : 0.f);
  float lself = selfa > 0.f ? selfa : 0.2f*selfa;
  float wself = __expf(lself);
  p += wself;
  {
    uint2 q = *(const uint2*)(Hb + (size_t)v*128 + c0);
    acc[0] = fmaf(wself, __uint_as_float(q.x << 16), acc[0]);
    acc[1] = fmaf(wself, __uint_as_float(q.x & 0xFFFF0000u), acc[1]);
    acc[2] = fmaf(wself, __uint_as_float(q.y << 16), acc[2]);
    acc[3] = fmaf(wself, __uint_as_float(q.y & 0xFFFF0000u), acc[3]);
  }
  float inv = 1.f / p;
  float o0 = fmaxf(acc[0]*inv + bv.x, 0.f);
  float o1 = fmaxf(acc[1]*inv + bv.y, 0.f);
  float o2 = fmaxf(acc[2]*inv + bv.z, 0.f);
  float o3 = fmaxf(acc[3]*inv + bv.w, 0.f);
  if (HAS_EW){
    uint2 r = *(const uint2*)(residb + (size_t)v*128 + c0);
    o0 += __uint_as_float(r.x << 16);
    o1 += __uint_as_float(r.x & 0xFFFF0000u);
    o2 += __uint_as_float(r.y << 16);
    o3 += __uint_as_float(r.y & 0xFFFF0000u);
  }
  uint2 ow;
  ow.x = (unsigned)f2bf(o0) | ((unsigned)f2bf(o1) << 16);
  ow.y = (unsigned)f2bf(o2) | ((unsigned)f2bf(o3) << 16);
  *(uint2*)(out + (size_t)v*128 + c0) = ow;
}

// ---- fused mu+ls aggregation: 32-lane group per node, degree-sorted, interleaved Y ----
__global__ __launch_bounds__(256) void agg_muls(const unsigned short* __restrict__ Yb,
                                                const float2* __restrict__ sg,
                                                const float2* __restrict__ dg,
                                                const float2* __restrict__ ewpmuls,
                                                const int* __restrict__ rowptr,
                                                const unsigned* __restrict__ csr_u,
                                                const int* __restrict__ perm,
                                                const float* __restrict__ bmu,
                                                const float* __restrict__ bls,
                                                float* __restrict__ outmu,
                                                float* __restrict__ outls){
  int g = (blockIdx.x * blockDim.x + threadIdx.x) >> 5;
  int lig = threadIdx.x & 31;
  if (g >= NN) return;
  int v = perm[g];
  int rs = rowptr[v], re = rowptr[v+1];
  int deg = re - rs;
  float2 dv = dg[v];
  int c0 = lig*2;
  float2 bmv = make_float2(bmu[c0], bmu[c0+1]);
  float2 blv = make_float2(bls[c0], bls[c0+1]);
  float accmu[2] = {0.f,0.f}, accls[2] = {0.f,0.f};
  float pmu = 0.f, pls = 0.f, ewlmu = 0.f, ewlls = 0.f;
  for (int base = rs; base < re; base += 32){
    int i = base + lig;
    int u = 0; float wmu = 0.f, wls = 0.f;
    if (i < re){
      u = (int)csr_u[i];
      float2 su = sg[u];
      float2 ee = ewpmuls[i];
      ewlmu += ee.x; ewlls += ee.y;
      float amu = su.x + dv.x + ee.x;
      float als = su.y + dv.y + ee.y;
      float lmu = amu > 0.f ? amu : 0.2f*amu;
      float lls = als > 0.f ? als : 0.2f*als;
      wmu = __expf(lmu); wls = __expf(lls);
    }
    pmu += wmu; pls += wls;
    int nv = re - base; if (nv > 32) nv = 32;
    for (int j = 0; j < nv; j += 8){
      uint2 q[8]; float wm[8], wl[8];
      #pragma unroll
      for (int k = 0; k < 8; k++){
        int uk = __shfl(u, j+k, 32);
        wm[k] = __shfl(wmu, j+k, 32);
        wl[k] = __shfl(wls, j+k, 32);
        q[k] = *(const uint2*)(Yb + (size_t)uk*128 + lig*4);
      }
      #pragma unroll
      for (int k = 0; k < 8; k++){
        accmu[0] = fmaf(wm[k], __uint_as_float(q[k].x << 16), accmu[0]);
        accls[0] = fmaf(wl[k], __uint_as_float(q[k].x & 0xFFFF0000u), accls[0]);
        accmu[1] = fmaf(wm[k], __uint_as_float(q[k].y << 16), accmu[1]);
        accls[1] = fmaf(wl[k], __uint_as_float(q[k].y & 0xFFFF0000u), accls[1]);
      }
    }
  }
  float Pmu = grp_sum32(pmu), Pls = grp_sum32(pls);
  float Emu = grp_sum32(ewlmu), Els = grp_sum32(ewlls);
  float2 sv = sg[v];
  float dnm = (float)(deg > 1 ? deg : 1);
  float selfmu = sv.x + dv.x + Emu/dnm;
  float selfls = sv.y + dv.y + Els/dnm;
  float lmu = selfmu > 0.f ? selfmu : 0.2f*selfmu;
  float lls = selfls > 0.f ? selfls : 0.2f*selfls;
  float wmu_s = __expf(lmu), wls_s = __expf(lls);
  Pmu += wmu_s; Pls += wls_s;
  {
    uint2 q = *(const uint2*)(Yb + (size_t)v*128 + lig*4);
    accmu[0] = fmaf(wmu_s, __uint_as_float(q.x << 16), accmu[0]);
    accls[0] = fmaf(wls_s, __uint_as_float(q.x & 0xFFFF0000u), accls[0]);
    accmu[1] = fmaf(wmu_s, __uint_as_float(q.y << 16), accmu[1]);
    accls[1] = fmaf(wls_s, __uint_as_float(q.y & 0xFFFF0000u), accls[1]);
  }
  float imu = 1.f/Pmu, ils = 1.f/Pls;
  float2 omu = make_float2(accmu[0]*imu + bmv.x, accmu[1]*imu + bmv.y);
  float2 ols = make_float2(accls[0]*ils + blv.x, accls[1]*ils + blv.y);
  *(float2*)(outmu + (size_t)v*64 + c0) = omu;
  *(float2*)(outls + (size_t)v*64 + c0) = ols;
}

extern "C" void kernel_launch(void* const* d_in, const int* in_sizes, int n_in,
                              void* d_out, int out_size, void* d_ws, size_t ws_size,
                              hipStream_t stream){
  const float* x    = (const float*)d_in[0];
  const int*   ei   = (const int*)  d_in[1];
  const float* ea   = (const float*)d_in[2];
  const float* W1   = (const float*)d_in[3];
  const float* a1s  = (const float*)d_in[4];
  const float* a1d  = (const float*)d_in[5];
  const float* b1   = (const float*)d_in[6];
  const float* W2   = (const float*)d_in[7];
  const float* a2s  = (const float*)d_in[8];
  const float* a2d  = (const float*)d_in[9];
  const float* b2   = (const float*)d_in[10];
  const float* We2  = (const float*)d_in[11];
  const float* ae2  = (const float*)d_in[12];
  const float* Wr   = (const float*)d_in[13];
  const float* br   = (const float*)d_in[14];
  const float* Wmu  = (const float*)d_in[15];
  const float* amus = (const float*)d_in[16];
  const float* amud = (const float*)d_in[17];
  const float* bmu  = (const float*)d_in[18];
  const float* Wemu = (const float*)d_in[19];
  const float* aemu = (const float*)d_in[20];
  const float* Wls  = (const float*)d_in[21];
  const float* alss = (const float*)d_in[22];
  const float* alsd = (const float*)d_in[23];
  const float* bls  = (const float*)d_in[24];
  const float* Wels = (const float*)d_in[25];
  const float* aels = (const float*)d_in[26];

  char* base = (char*)d_ws;
  size_t off = 0;
  auto alloc = [&](size_t bytes)->char*{
    char* p = base + off;
    off = (off + bytes + 511) & ~(size_t)511;
    return p;
  };
  int*      rowptr = (int*)   alloc((size_t)(NN+1)*4);
  unsigned* gbcnt  = (unsigned*)alloc(640*4);   // gbcnt[256]+gbfill[256]+dcnt[64]+dfill[64]
  unsigned* gbfill = gbcnt + 256;
  unsigned* dcnt   = gbcnt + 512;
  unsigned* dfill  = gbcnt + 576;
  unsigned* gbbase = (unsigned*)alloc(257*4);
  unsigned* dbase  = (unsigned*)alloc(64*4);
  int*      perm   = (int*)   alloc((size_t)NN*4);
  uint2*    bdu    = (uint2*) alloc((size_t)NE*8);
  float4*   bw     = (float4*)alloc((size_t)NE*16);
  unsigned* csr_u  = (unsigned*)alloc((size_t)NE*4);
  float*    ewp2   = (float*) alloc((size_t)NE*4);
  float2*   ewpmls = (float2*)alloc((size_t)NE*8);
  float*    wv     = (float*) alloc(48*4);
  float*    s1     = (float*) alloc((size_t)NN*4);
  float*    d1     = (float*) alloc((size_t)NN*4);
  float2*   sg2    = (float2*)alloc((size_t)NN*8);
  float2*   dg2    = (float2*)alloc((size_t)NN*8);
  unsigned short* W1t  = (unsigned short*)alloc(128*128*2);
  unsigned short* W2t  = (unsigned short*)alloc(128*128*2);
  unsigned short* Wrt  = (unsigned short*)alloc(128*128*2);
  unsigned short* Wmlt = (unsigned short*)alloc(128*128*2);
  unsigned short* Xb   = (unsigned short*)alloc((size_t)NN*128*2);
  unsigned short* XRb  = (unsigned short*)alloc((size_t)NN*128*2);  // residual bf16
  unsigned short* bufA = (unsigned short*)alloc((size_t)NN*128*2);  // H1 -> H2 -> Y(muls)
  unsigned short* bufB = (unsigned short*)alloc((size_t)NN*128*2);  // h1 -> h
  if (off > ws_size) return;

  float* outF = (float*)d_out;   // [mu | logstd]
  float* muO  = outF;
  float* lsO  = outF + (size_t)NN*64;

  const int HB   = (NE + 4095)/4096;    // 1024-thread, 4 edges/thread
  const int WB32 = (NN*32 + 255)/256;   // one 32-lane group per node
  const int GB   = (NN + 127)/128;
  const int CB   = (NN*128/8 + 255)/256;

  // precompute + graph build
  prep_w_kernel<<<4, 256, 0, stream>>>(W1, W2, Wr, Wmu, Wls, W1t, W2t, Wrt, Wmlt);
  wvec_kernel<<<1, 64, 0, stream>>>(We2, ae2, Wemu, aemu, Wels, aels, wv);
  cast_x_kernel<<<CB, 256, 0, stream>>>(x, Xb);
  zero_kernel<<<3, 256, 0, stream>>>((int*)gbcnt, 640);
  ehist_kernel<<<HB, 1024, 0, stream>>>(ei, gbcnt);
  bscan_kernel<<<1, 256, 0, stream>>>(gbcnt, gbbase, rowptr);
  bin_kernel<<<HB, 1024, 0, stream>>>(ei, ea, wv, gbbase, gbfill, bdu, bw);
  place_kernel<<<NBUK, 1024, 0, stream>>>(bdu, bw, gbbase, rowptr, csr_u, ewp2, ewpmls);
  // degree counting sort -> perm
  dhist_kernel<<<NB, 256, 0, stream>>>(rowptr, dcnt);
  dscan_kernel<<<1, 64, 0, stream>>>(dcnt, dbase);
  dscatter_kernel<<<NB, 256, 0, stream>>>(rowptr, dbase, dfill, perm);

  // conv1 (dots fused into GEMM epilogue)
  gemm_bf16<0,1><<<GB, 256, 0, stream>>>(Xb, W1t, bufA, nullptr, NN,
                                         a1s, a1d, nullptr, nullptr, s1, d1);     // H1
  agg_conv<false><<<WB32, 256, 0, stream>>>(bufA, s1, d1, nullptr, rowptr, csr_u,
                                            perm, b1, nullptr, bufB);             // h1
  // conv2 + residual (XR in bf16)
  gemm_bf16<0,1><<<GB, 256, 0, stream>>>(bufB, W2t, bufA, nullptr, NN,
                                         a2s, a2d, nullptr, nullptr, s1, d1);     // H2
  gemm_bf16<2,0><<<GB, 256, 0, stream>>>(Xb, Wrt, XRb, br, NN,
                                         nullptr, nullptr, nullptr, nullptr,
                                         nullptr, nullptr);                       // XR bf16
  agg_conv<true><<<WB32, 256, 0, stream>>>(bufA, s1, d1, ewp2, rowptr, csr_u,
                                           perm, b2, XRb, bufB);                  // h
  // mu + logstd (fused, interleaved; dots fused into GEMM)
  gemm_bf16<0,2><<<GB, 256, 0, stream>>>(bufB, Wmlt, bufA, nullptr, NN,
                                         amus, amud, alss, alsd,
                                         (float*)sg2, (float*)dg2);               // Y interleaved
  agg_muls<<<WB32, 256, 0, stream>>>(bufA, sg2, dg2, ewpmls, rowptr, csr_u,
                                     perm, bmu, bls, muO, lsO);
}

// Round 12
// 450.848 us; speedup vs baseline: 2.3299x; 1.0656x over previous
//
#include <hip/hip_runtime.h>

#define NN 100000
#define NE 1600000
#define BSH 9
#define NBUK 196          // ceil(NN / 512)

typedef __attribute__((ext_vector_type(8))) short bf16x8;
typedef __attribute__((ext_vector_type(4))) float f32x4;

__device__ __forceinline__ float grp_sum16(float v){
  #pragma unroll
  for (int o = 8; o; o >>= 1) v += __shfl_xor(v, o, 16);
  return v;
}
__device__ __forceinline__ float grp_sum32(float v){
  #pragma unroll
  for (int o = 16; o; o >>= 1) v += __shfl_xor(v, o, 32);
  return v;
}
__device__ __forceinline__ float bf2f(unsigned short x){
  return __uint_as_float(((unsigned)x) << 16);
}
__device__ __forceinline__ unsigned short f2bf(float f){
  unsigned u = __float_as_uint(f);
  return (unsigned short)((u + 0x7FFFu + ((u >> 16) & 1u)) >> 16);
}

// ---- weight prep: transpose + bf16. Wmlt interleaved: col 2c=Wmu[:,c], 2c+1=Wls[:,c] ----
__global__ void prep_w_kernel(const float* __restrict__ W1, const float* __restrict__ W2,
                              const float* __restrict__ Wr, const float* __restrict__ Wmu,
                              const float* __restrict__ Wls,
                              unsigned short* __restrict__ W1t, unsigned short* __restrict__ W2t,
                              unsigned short* __restrict__ Wrt, unsigned short* __restrict__ Wmlt){
  int b = blockIdx.x, t = threadIdx.x;
  for (int it = 0; it < 64; it++){
    int idx = it*256 + t;          // 16384 entries
    int k = idx >> 7, c = idx & 127;
    float v; unsigned short* dst;
    if (b == 0){ v = W1[k*128+c]; dst = W1t; }
    else if (b == 1){ v = W2[k*128+c]; dst = W2t; }
    else if (b == 2){ v = Wr[k*128+c]; dst = Wrt; }
    else { v = (c & 1) ? Wls[k*64 + (c>>1)] : Wmu[k*64 + (c>>1)]; dst = Wmlt; }
    dst[c*128 + k] = f2bf(v);      // [col][k]
  }
}

__global__ void wvec_kernel(const float* __restrict__ We2, const float* __restrict__ ae2,
                            const float* __restrict__ Wemu, const float* __restrict__ aemu,
                            const float* __restrict__ Wels, const float* __restrict__ aels,
                            float* __restrict__ wv){
  int t = threadIdx.x;
  if (t < 16){
    float s = 0.f; for (int c = 0; c < 128; c++) s += We2[t*128+c]*ae2[c];
    wv[t] = s;
  } else if (t < 32){
    int k = t-16; float s = 0.f; for (int c = 0; c < 64; c++) s += Wemu[k*64+c]*aemu[c];
    wv[16+k] = s;
  } else if (t < 48){
    int k = t-32; float s = 0.f; for (int c = 0; c < 64; c++) s += Wels[k*64+c]*aels[c];
    wv[32+k] = s;
  }
}

__global__ void cast_x_kernel(const float* __restrict__ x, unsigned short* __restrict__ Xb){
  int i = blockIdx.x*256 + threadIdx.x;   // 8 elems each
  if (i >= NN*128/8) return;
  const float4* src = (const float4*)x + (size_t)i*2;
  float4 v0 = src[0], v1 = src[1];
  ushort4 o0 = make_ushort4(f2bf(v0.x), f2bf(v0.y), f2bf(v0.z), f2bf(v0.w));
  ushort4 o1 = make_ushort4(f2bf(v1.x), f2bf(v1.y), f2bf(v1.z), f2bf(v1.w));
  *(ushort4*)(Xb + (size_t)i*8)     = o0;
  *(ushort4*)(Xb + (size_t)i*8 + 4) = o1;
}

__global__ void zero_kernel(int* __restrict__ p, int n){
  int i = blockIdx.x*256 + threadIdx.x;
  if (i < n) p[i] = 0;
}

// ---- coarse 256-bucket histogram of dst>>9 (LDS aggregated) ----
__global__ __launch_bounds__(1024) void ehist_kernel(const int* __restrict__ ei,
                                                     unsigned* __restrict__ gbcnt){
  __shared__ unsigned h[256];
  int t = threadIdx.x;
  if (t < 256) h[t] = 0;
  __syncthreads();
  int e0 = blockIdx.x*4096 + t;
  #pragma unroll
  for (int k = 0; k < 4; k++){
    int e = e0 + k*1024;
    if (e < NE) atomicAdd(&h[ei[NE+e] >> BSH], 1);
  }
  __syncthreads();
  if (t < 256 && h[t]) atomicAdd(&gbcnt[t], h[t]);
}

__global__ void bscan_kernel(const unsigned* __restrict__ gbcnt,
                             unsigned* __restrict__ gbbase, int* __restrict__ rowptr){
  __shared__ unsigned sh[256];
  int t = threadIdx.x;   // 256
  unsigned v = gbcnt[t];
  sh[t] = v; __syncthreads();
  for (int o = 1; o < 256; o <<= 1){
    unsigned add = (t >= o) ? sh[t-o] : 0;
    __syncthreads();
    sh[t] += add;
    __syncthreads();
  }
  gbbase[t+1] = sh[t];
  if (t == 0){ gbbase[0] = 0; rowptr[NN] = NE; }
}

// ---- bin (+fused edge-scalar dots): append {dst,u} + {s2,smu,sls} per bucket ----
__global__ __launch_bounds__(1024) void bin_kernel(const int* __restrict__ ei,
                                                   const float* __restrict__ ea,
                                                   const float* __restrict__ wv,
                                                   const unsigned* __restrict__ gbbase,
                                                   unsigned* __restrict__ gbfill,
                                                   uint2* __restrict__ bdu,
                                                   float4* __restrict__ bw){
  __shared__ unsigned hcnt[256], hbase[256], hcur[256];
  __shared__ float wvs[48];
  int t = threadIdx.x;
  if (t < 256){ hcnt[t] = 0; hcur[t] = 0; }
  else if (t >= 256 && t < 304) wvs[t-256] = wv[t-256];
  __syncthreads();
  int d[4], u[4], b[4]; float4 w[4]; bool val[4];
  int e0 = blockIdx.x*4096 + t;
  #pragma unroll
  for (int k = 0; k < 4; k++){
    int e = e0 + k*1024;
    val[k] = e < NE;
    if (val[k]){
      d[k] = ei[NE+e]; u[k] = ei[e];
      b[k] = d[k] >> BSH;
      atomicAdd(&hcnt[b[k]], 1);
      const float4* p = (const float4*)(ea + (size_t)e*16);
      float a[16]; float4 vv;
      vv = p[0]; a[0]=vv.x; a[1]=vv.y; a[2]=vv.z; a[3]=vv.w;
      vv = p[1]; a[4]=vv.x; a[5]=vv.y; a[6]=vv.z; a[7]=vv.w;
      vv = p[2]; a[8]=vv.x; a[9]=vv.y; a[10]=vv.z; a[11]=vv.w;
      vv = p[3]; a[12]=vv.x; a[13]=vv.y; a[14]=vv.z; a[15]=vv.w;
      float s2 = 0.f, smu = 0.f, sls = 0.f;
      #pragma unroll
      for (int q = 0; q < 16; q++){
        s2  = fmaf(a[q], wvs[q],    s2);
        smu = fmaf(a[q], wvs[16+q], smu);
        sls = fmaf(a[q], wvs[32+q], sls);
      }
      w[k] = make_float4(s2, smu, sls, 0.f);
    }
  }
  __syncthreads();
  if (t < 256){
    unsigned c = hcnt[t];
    hbase[t] = c ? atomicAdd(&gbfill[t], c) : 0u;
  }
  __syncthreads();
  #pragma unroll
  for (int k = 0; k < 4; k++){
    if (val[k]){
      unsigned pos = atomicAdd(&hcur[b[k]], 1);
      unsigned slot = gbbase[b[k]] + hbase[b[k]] + pos;
      bdu[slot] = make_uint2((unsigned)d[k], (unsigned)u[k]);
      bw[slot]  = w[k];
    }
  }
}

// ---- place: per-bucket sub-rowptr in LDS + scatter into L2-resident CSR region ----
__global__ __launch_bounds__(1024) void place_kernel(const uint2* __restrict__ bdu,
                                                     const float4* __restrict__ bw,
                                                     const unsigned* __restrict__ gbbase,
                                                     int* __restrict__ rowptr,
                                                     unsigned* __restrict__ csr_u,
                                                     float* __restrict__ ewp2,
                                                     float2* __restrict__ ewpmuls){
  __shared__ unsigned h[512], incl[512], cur[512];
  int b = blockIdx.x, t = threadIdx.x;
  unsigned cbase = gbbase[b];
  unsigned cnt = gbbase[b+1] - cbase;
  if (t < 512) h[t] = 0;
  __syncthreads();
  for (unsigned i = t; i < cnt; i += 1024)
    atomicAdd(&h[bdu[cbase+i].x & 511], 1);
  __syncthreads();
  if (t < 512) incl[t] = h[t];
  __syncthreads();
  for (int o = 1; o < 512; o <<= 1){
    unsigned add = (t >= o && t < 512) ? incl[t-o] : 0;
    __syncthreads();
    if (t < 512) incl[t] += add;
    __syncthreads();
  }
  if (t < 512){
    cur[t] = 0;
    int node = (b << BSH) + t;
    if (node < NN) rowptr[node] = (int)(cbase + incl[t] - h[t]);
  }
  __syncthreads();
  for (unsigned i = t; i < cnt; i += 1024){
    uint2 du = bdu[cbase+i];
    unsigned ld = du.x & 511;
    unsigned pos = atomicAdd(&cur[ld], 1);
    unsigned slot = cbase + (incl[ld] - h[ld]) + pos;
    float4 w = bw[cbase+i];
    csr_u[slot] = du.y;
    ewp2[slot] = w.x;
    ewpmuls[slot] = make_float2(w.y, w.z);
  }
}

// ---- MFMA GEMM: Y[nrows x 128] = Xb @ Wt^T, bf16 in, fp32 acc.
//      OUT: 0=bf16, 1=f32+bias, 2=bf16+bias. DOTS: 0 none, 1 conv s/d, 2 mu/ls. ----
template<int OUT, int DOTS>
__global__ __launch_bounds__(256) void gemm_bf16(const unsigned short* __restrict__ Xb,
                                                 const unsigned short* __restrict__ Wt,
                                                 void* __restrict__ Y,
                                                 const float* __restrict__ bias, int nrows,
                                                 const float* __restrict__ va,
                                                 const float* __restrict__ vb,
                                                 const float* __restrict__ vc,
                                                 const float* __restrict__ vd,
                                                 float* __restrict__ sOut,
                                                 float* __restrict__ dOut){
  __shared__ uint4 As[128*16];   // 32 KB, XOR-swizzled chunks
  __shared__ uint4 Bs[128*16];   // 32 KB
  int t = threadIdx.x;
  int row0 = blockIdx.x * 128;
  #pragma unroll
  for (int p = 0; p < 8; p++){
    int idx = p*256 + t;
    int r = idx >> 4, cir = idx & 15;
    uint4 v = make_uint4(0,0,0,0);
    if (row0 + r < nrows) v = *(const uint4*)(Xb + ((size_t)(row0+r))*128 + cir*8);
    As[r*16 + (cir ^ (r & 7))] = v;
  }
  #pragma unroll
  for (int p = 0; p < 8; p++){
    int idx = p*256 + t;
    int r = idx >> 4, cir = idx & 15;
    Bs[r*16 + (cir ^ (r & 7))] = *(const uint4*)(Wt + (size_t)r*128 + cir*8);
  }
  __syncthreads();
  int w = t >> 6, l = t & 63;
  int lr = l & 15;
  int lk = l >> 4;
  const bf16x8* As8 = (const bf16x8*)As;
  const bf16x8* Bs8 = (const bf16x8*)Bs;
  f32x4 acc[2][8];
  f32x4 zero = {0.f, 0.f, 0.f, 0.f};
  #pragma unroll
  for (int m = 0; m < 2; m++)
    #pragma unroll
    for (int n = 0; n < 8; n++) acc[m][n] = zero;
  #pragma unroll
  for (int ks = 0; ks < 4; ks++){
    bf16x8 a0, a1, bf[8];
    { int r = w*32 + lr;      a0 = As8[r*16 + ((ks*4+lk) ^ (r&7))]; }
    { int r = w*32 + 16 + lr; a1 = As8[r*16 + ((ks*4+lk) ^ (r&7))]; }
    #pragma unroll
    for (int nt = 0; nt < 8; nt++){
      int r = nt*16 + lr;
      bf[nt] = Bs8[r*16 + ((ks*4+lk) ^ (r&7))];
    }
    #pragma unroll
    for (int nt = 0; nt < 8; nt++){
      acc[0][nt] = __builtin_amdgcn_mfma_f32_16x16x32_bf16(a0, bf[nt], acc[0][nt], 0, 0, 0);
      acc[1][nt] = __builtin_amdgcn_mfma_f32_16x16x32_bf16(a1, bf[nt], acc[1][nt], 0, 0, 0);
    }
  }
  if constexpr (DOTS == 1){
    #pragma unroll
    for (int mt = 0; mt < 2; mt++){
      #pragma unroll
      for (int i = 0; i < 4; i++){
        float ps = 0.f, pd = 0.f;
        #pragma unroll
        for (int nt = 0; nt < 8; nt++){
          float av = acc[mt][nt][i];
          int col = nt*16 + lr;
          ps = fmaf(av, va[col], ps);
          pd = fmaf(av, vb[col], pd);
        }
        ps = grp_sum16(ps); pd = grp_sum16(pd);
        int r = row0 + w*32 + mt*16 + lk*4 + i;
        if (lr == 0 && r < nrows){ sOut[r] = ps; dOut[r] = pd; }
      }
    }
  }
  if constexpr (DOTS == 2){
    #pragma unroll
    for (int mt = 0; mt < 2; mt++){
      #pragma unroll
      for (int i = 0; i < 4; i++){
        float pmu = 0.f, pdm = 0.f, pls = 0.f, pdl = 0.f;
        #pragma unroll
        for (int nt = 0; nt < 8; nt++){
          float av = acc[mt][nt][i];
          int col = nt*16 + lr;
          int c = col >> 1;
          if (col & 1){ pls = fmaf(av, vc[c], pls); pdl = fmaf(av, vd[c], pdl); }
          else        { pmu = fmaf(av, va[c], pmu); pdm = fmaf(av, vb[c], pdm); }
        }
        pmu = grp_sum16(pmu); pdm = grp_sum16(pdm);
        pls = grp_sum16(pls); pdl = grp_sum16(pdl);
        int r = row0 + w*32 + mt*16 + lk*4 + i;
        if (lr == 0 && r < nrows){
          ((float2*)sOut)[r] = make_float2(pmu, pls);
          ((float2*)dOut)[r] = make_float2(pdm, pdl);
        }
      }
    }
  }
  #pragma unroll
  for (int mt = 0; mt < 2; mt++){
    int gr0 = row0 + w*32 + mt*16 + lk*4;
    #pragma unroll
    for (int nt = 0; nt < 8; nt++){
      int col = nt*16 + lr;
      float bv = (OUT >= 1) ? bias[col] : 0.f;
      #pragma unroll
      for (int i = 0; i < 4; i++){
        int r = gr0 + i;
        if (r < nrows){
          float o = acc[mt][nt][i] + bv;
          if constexpr (OUT == 1) ((float*)Y)[(size_t)r*128 + col] = o;
          else ((unsigned short*)Y)[(size_t)r*128 + col] = f2bf(o);
        }
      }
    }
  }
}

// ---- conv aggregation: 32-lane group per node (R7 structure), 8-deep gather ----
template<bool HAS_EW>
__global__ __launch_bounds__(256) void agg_conv(const unsigned short* __restrict__ Hb,
                                                const float* __restrict__ s,
                                                const float* __restrict__ dsc,
                                                const float* __restrict__ ewp,
                                                const int* __restrict__ rowptr,
                                                const unsigned* __restrict__ csr_u,
                                                const float* __restrict__ bias,
                                                const unsigned short* __restrict__ residb,
                                                unsigned short* __restrict__ out){
  int v = (blockIdx.x * blockDim.x + threadIdx.x) >> 5;
  int lig = threadIdx.x & 31;
  if (v >= NN) return;
  int rs = rowptr[v], re = rowptr[v+1];
  int deg = re - rs;
  float d_v = dsc[v];
  int c0 = lig*4;
  float4 bv = *(const float4*)(bias + c0);
  float acc[4] = {0.f,0.f,0.f,0.f};
  float pl = 0.f, ewl = 0.f;
  for (int base = rs; base < re; base += 32){
    int i = base + lig;
    int u = 0; float w = 0.f;
    if (i < re){
      u = (int)csr_u[i];
      float e = HAS_EW ? ewp[i] : 0.f;
      if (HAS_EW) ewl += e;
      float a = s[u] + d_v + e;
      float l = a > 0.f ? a : 0.2f*a;
      w = __expf(l);
    }
    pl += w;
    int nv = re - base; if (nv > 32) nv = 32;
    for (int j = 0; j < nv; j += 8){
      uint2 q[8]; float wj[8];
      #pragma unroll
      for (int k = 0; k < 8; k++){
        int uk = __shfl(u, j+k, 32);
        wj[k] = __shfl(w, j+k, 32);
        q[k] = *(const uint2*)(Hb + (size_t)uk*128 + c0);
      }
      #pragma unroll
      for (int k = 0; k < 8; k++){
        acc[0] = fmaf(wj[k], __uint_as_float(q[k].x << 16), acc[0]);
        acc[1] = fmaf(wj[k], __uint_as_float(q[k].x & 0xFFFF0000u), acc[1]);
        acc[2] = fmaf(wj[k], __uint_as_float(q[k].y << 16), acc[2]);
        acc[3] = fmaf(wj[k], __uint_as_float(q[k].y & 0xFFFF0000u), acc[3]);
      }
    }
  }
  float p = grp_sum32(pl);
  float ews = HAS_EW ? grp_sum32(ewl) : 0.f;
  float selfa = s[v] + d_v + (HAS_EW ? ews / (float)(deg > 1 ? deg : 1) : 0.f);
  float lself = selfa > 0.f ? selfa : 0.2f*selfa;
  float wself = __expf(lself);
  p += wself;
  {
    uint2 q = *(const uint2*)(Hb + (size_t)v*128 + c0);
    acc[0] = fmaf(wself, __uint_as_float(q.x << 16), acc[0]);
    acc[1] = fmaf(wself, __uint_as_float(q.x & 0xFFFF0000u), acc[1]);
    acc[2] = fmaf(wself, __uint_as_float(q.y << 16), acc[2]);
    acc[3] = fmaf(wself, __uint_as_float(q.y & 0xFFFF0000u), acc[3]);
  }
  float inv = 1.f / p;
  float o0 = fmaxf(acc[0]*inv + bv.x, 0.f);
  float o1 = fmaxf(acc[1]*inv + bv.y, 0.f);
  float o2 = fmaxf(acc[2]*inv + bv.z, 0.f);
  float o3 = fmaxf(acc[3]*inv + bv.w, 0.f);
  if (HAS_EW){
    uint2 r = *(const uint2*)(residb + (size_t)v*128 + c0);
    o0 += __uint_as_float(r.x << 16);
    o1 += __uint_as_float(r.x & 0xFFFF0000u);
    o2 += __uint_as_float(r.y << 16);
    o3 += __uint_as_float(r.y & 0xFFFF0000u);
  }
  uint2 ow;
  ow.x = (unsigned)f2bf(o0) | ((unsigned)f2bf(o1) << 16);
  ow.y = (unsigned)f2bf(o2) | ((unsigned)f2bf(o3) << 16);
  *(uint2*)(out + (size_t)v*128 + c0) = ow;
}

// ---- fused mu+ls aggregation: 32-lane group per node, interleaved Y ----
__global__ __launch_bounds__(256) void agg_muls(const unsigned short* __restrict__ Yb,
                                                const float2* __restrict__ sg,
                                                const float2* __restrict__ dg,
                                                const float2* __restrict__ ewpmuls,
                                                const int* __restrict__ rowptr,
                                                const unsigned* __restrict__ csr_u,
                                                const float* __restrict__ bmu,
                                                const float* __restrict__ bls,
                                                float* __restrict__ outmu,
                                                float* __restrict__ outls){
  int v = (blockIdx.x * blockDim.x + threadIdx.x) >> 5;
  int lig = threadIdx.x & 31;
  if (v >= NN) return;
  int rs = rowptr[v], re = rowptr[v+1];
  int deg = re - rs;
  float2 dv = dg[v];
  int c0 = lig*2;
  float2 bmv = make_float2(bmu[c0], bmu[c0+1]);
  float2 blv = make_float2(bls[c0], bls[c0+1]);
  float accmu[2] = {0.f,0.f}, accls[2] = {0.f,0.f};
  float pmu = 0.f, pls = 0.f, ewlmu = 0.f, ewlls = 0.f;
  for (int base = rs; base < re; base += 32){
    int i = base + lig;
    int u = 0; float wmu = 0.f, wls = 0.f;
    if (i < re){
      u = (int)csr_u[i];
      float2 su = sg[u];
      float2 ee = ewpmuls[i];
      ewlmu += ee.x; ewlls += ee.y;
      float amu = su.x + dv.x + ee.x;
      float als = su.y + dv.y + ee.y;
      float lmu = amu > 0.f ? amu : 0.2f*amu;
      float lls = als > 0.f ? als : 0.2f*als;
      wmu = __expf(lmu); wls = __expf(lls);
    }
    pmu += wmu; pls += wls;
    int nv = re - base; if (nv > 32) nv = 32;
    for (int j = 0; j < nv; j += 8){
      uint2 q[8]; float wm[8], wl[8];
      #pragma unroll
      for (int k = 0; k < 8; k++){
        int uk = __shfl(u, j+k, 32);
        wm[k] = __shfl(wmu, j+k, 32);
        wl[k] = __shfl(wls, j+k, 32);
        q[k] = *(const uint2*)(Yb + (size_t)uk*128 + lig*4);
      }
      #pragma unroll
      for (int k = 0; k < 8; k++){
        accmu[0] = fmaf(wm[k], __uint_as_float(q[k].x << 16), accmu[0]);
        accls[0] = fmaf(wl[k], __uint_as_float(q[k].x & 0xFFFF0000u), accls[0]);
        accmu[1] = fmaf(wm[k], __uint_as_float(q[k].y << 16), accmu[1]);
        accls[1] = fmaf(wl[k], __uint_as_float(q[k].y & 0xFFFF0000u), accls[1]);
      }
    }
  }
  float Pmu = grp_sum32(pmu), Pls = grp_sum32(pls);
  float Emu = grp_sum32(ewlmu), Els = grp_sum32(ewlls);
  float2 sv = sg[v];
  float dnm = (float)(deg > 1 ? deg : 1);
  float selfmu = sv.x + dv.x + Emu/dnm;
  float selfls = sv.y + dv.y + Els/dnm;
  float lmu = selfmu > 0.f ? selfmu : 0.2f*selfmu;
  float lls = selfls > 0.f ? selfls : 0.2f*selfls;
  float wmu_s = __expf(lmu), wls_s = __expf(lls);
  Pmu += wmu_s; Pls += wls_s;
  {
    uint2 q = *(const uint2*)(Yb + (size_t)v*128 + lig*4);
    accmu[0] = fmaf(wmu_s, __uint_as_float(q.x << 16), accmu[0]);
    accls[0] = fmaf(wls_s, __uint_as_float(q.x & 0xFFFF0000u), accls[0]);
    accmu[1] = fmaf(wmu_s, __uint_as_float(q.y << 16), accmu[1]);
    accls[1] = fmaf(wls_s, __uint_as_float(q.y & 0xFFFF0000u), accls[1]);
  }
  float imu = 1.f/Pmu, ils = 1.f/Pls;
  float2 omu = make_float2(accmu[0]*imu + bmv.x, accmu[1]*imu + bmv.y);
  float2 ols = make_float2(accls[0]*ils + blv.x, accls[1]*ils + blv.y);
  *(float2*)(outmu + (size_t)v*64 + c0) = omu;
  *(float2*)(outls + (size_t)v*64 + c0) = ols;
}

extern "C" void kernel_launch(void* const* d_in, const int* in_sizes, int n_in,
                              void* d_out, int out_size, void* d_ws, size_t ws_size,
                              hipStream_t stream){
  const float* x    = (const float*)d_in[0];
  const int*   ei   = (const int*)  d_in[1];
  const float* ea   = (const float*)d_in[2];
  const float* W1   = (const float*)d_in[3];
  const float* a1s  = (const float*)d_in[4];
  const float* a1d  = (const float*)d_in[5];
  const float* b1   = (const float*)d_in[6];
  const float* W2   = (const float*)d_in[7];
  const float* a2s  = (const float*)d_in[8];
  const float* a2d  = (const float*)d_in[9];
  const float* b2   = (const float*)d_in[10];
  const float* We2  = (const float*)d_in[11];
  const float* ae2  = (const float*)d_in[12];
  const float* Wr   = (const float*)d_in[13];
  const float* br   = (const float*)d_in[14];
  const float* Wmu  = (const float*)d_in[15];
  const float* amus = (const float*)d_in[16];
  const float* amud = (const float*)d_in[17];
  const float* bmu  = (const float*)d_in[18];
  const float* Wemu = (const float*)d_in[19];
  const float* aemu = (const float*)d_in[20];
  const float* Wls  = (const float*)d_in[21];
  const float* alss = (const float*)d_in[22];
  const float* alsd = (const float*)d_in[23];
  const float* bls  = (const float*)d_in[24];
  const float* Wels = (const float*)d_in[25];
  const float* aels = (const float*)d_in[26];

  char* base = (char*)d_ws;
  size_t off = 0;
  auto alloc = [&](size_t bytes)->char*{
    char* p = base + off;
    off = (off + bytes + 511) & ~(size_t)511;
    return p;
  };
  int*      rowptr = (int*)   alloc((size_t)(NN+1)*4);
  unsigned* gbcnt  = (unsigned*)alloc(512*4);        // gbcnt[256] + gbfill[256]
  unsigned* gbfill = gbcnt + 256;
  unsigned* gbbase = (unsigned*)alloc(257*4);
  uint2*    bdu    = (uint2*) alloc((size_t)NE*8);
  float4*   bw     = (float4*)alloc((size_t)NE*16);
  unsigned* csr_u  = (unsigned*)alloc((size_t)NE*4);
  float*    ewp2   = (float*) alloc((size_t)NE*4);
  float2*   ewpmls = (float2*)alloc((size_t)NE*8);
  float*    wv     = (float*) alloc(48*4);
  float*    s1     = (float*) alloc((size_t)NN*4);
  float*    d1     = (float*) alloc((size_t)NN*4);
  float2*   sg2    = (float2*)alloc((size_t)NN*8);
  float2*   dg2    = (float2*)alloc((size_t)NN*8);
  unsigned short* W1t  = (unsigned short*)alloc(128*128*2);
  unsigned short* W2t  = (unsigned short*)alloc(128*128*2);
  unsigned short* Wrt  = (unsigned short*)alloc(128*128*2);
  unsigned short* Wmlt = (unsigned short*)alloc(128*128*2);
  unsigned short* Xb   = (unsigned short*)alloc((size_t)NN*128*2);
  unsigned short* XRb  = (unsigned short*)alloc((size_t)NN*128*2);  // residual bf16
  unsigned short* bufA = (unsigned short*)alloc((size_t)NN*128*2);  // H1 -> H2 -> Y(muls)
  unsigned short* bufB = (unsigned short*)alloc((size_t)NN*128*2);  // h1 -> h
  if (off > ws_size) return;

  float* outF = (float*)d_out;   // [mu | logstd]
  float* muO  = outF;
  float* lsO  = outF + (size_t)NN*64;

  const int HB   = (NE + 4095)/4096;    // 1024-thread, 4 edges/thread
  const int WB32 = (NN*32 + 255)/256;   // one 32-lane group per node
  const int GB   = (NN + 127)/128;
  const int CB   = (NN*128/8 + 255)/256;

  // precompute + graph build
  prep_w_kernel<<<4, 256, 0, stream>>>(W1, W2, Wr, Wmu, Wls, W1t, W2t, Wrt, Wmlt);
  wvec_kernel<<<1, 64, 0, stream>>>(We2, ae2, Wemu, aemu, Wels, aels, wv);
  cast_x_kernel<<<CB, 256, 0, stream>>>(x, Xb);
  zero_kernel<<<2, 256, 0, stream>>>((int*)gbcnt, 512);
  ehist_kernel<<<HB, 1024, 0, stream>>>(ei, gbcnt);
  bscan_kernel<<<1, 256, 0, stream>>>(gbcnt, gbbase, rowptr);
  bin_kernel<<<HB, 1024, 0, stream>>>(ei, ea, wv, gbbase, gbfill, bdu, bw);
  place_kernel<<<NBUK, 1024, 0, stream>>>(bdu, bw, gbbase, rowptr, csr_u, ewp2, ewpmls);

  // conv1 (dots fused into GEMM epilogue)
  gemm_bf16<0,1><<<GB, 256, 0, stream>>>(Xb, W1t, bufA, nullptr, NN,
                                         a1s, a1d, nullptr, nullptr, s1, d1);     // H1
  agg_conv<false><<<WB32, 256, 0, stream>>>(bufA, s1, d1, nullptr, rowptr, csr_u,
                                            b1, nullptr, bufB);                   // h1
  // conv2 + residual (XR in bf16)
  gemm_bf16<0,1><<<GB, 256, 0, stream>>>(bufB, W2t, bufA, nullptr, NN,
                                         a2s, a2d, nullptr, nullptr, s1, d1);     // H2
  gemm_bf16<2,0><<<GB, 256, 0, stream>>>(Xb, Wrt, XRb, br, NN,
                                         nullptr, nullptr, nullptr, nullptr,
                                         nullptr, nullptr);                       // XR bf16
  agg_conv<true><<<WB32, 256, 0, stream>>>(bufA, s1, d1, ewp2, rowptr, csr_u,
                                           b2, XRb, bufB);                        // h
  // mu + logstd (fused, interleaved; dots fused into GEMM)
  gemm_bf16<0,2><<<GB, 256, 0, stream>>>(bufB, Wmlt, bufA, nullptr, NN,
                                         amus, amud, alss, alsd,
                                         (float*)sg2, (float*)dg2);               // Y interleaved
  agg_muls<<<WB32, 256, 0, stream>>>(bufA, sg2, dg2, ewpmls, rowptr, csr_u,
                                     bmu, bls, muO, lsO);
}